// Round 1
// baseline (912.564 us; speedup 1.0000x reference)
//
#include <hip/hip_runtime.h>
#include <stdint.h>

typedef unsigned short u16;
typedef __bf16 bf16x8 __attribute__((ext_vector_type(8)));
typedef float f32x4 __attribute__((ext_vector_type(4)));

#define AS1 __attribute__((address_space(1)))
#define AS3 __attribute__((address_space(3)))

__device__ __forceinline__ void g2l16(const void* g, void* l) {
  __builtin_amdgcn_global_load_lds((AS1 void*)(void*)g, (AS3 void*)l, 16, 0, 0);
}

__device__ __forceinline__ u16 f2bf(float f) {
  union { float f; uint32_t u; } v; v.f = f;
  return (u16)((v.u + 0x7fffu + ((v.u >> 16) & 1u)) >> 16);
}
__device__ __forceinline__ float bf2f(u16 b) {
  union { uint32_t u; float f; } v; v.u = ((uint32_t)b) << 16;
  return v.f;
}

// inline-asm ds_read (keeps backend from auto-inserting conservative waits;
// we place lgkmcnt(0)+sched_barrier(0) manually per rule #18)
__device__ __forceinline__ bf16x8 dsr(uint32_t a) {
  bf16x8 r;
  asm volatile("ds_read_b128 %0, %1" : "=v"(r) : "v"(a));
  return r;
}
__device__ __forceinline__ void barx() {
  __builtin_amdgcn_sched_barrier(0);
  __builtin_amdgcn_s_barrier();
  __builtin_amdgcn_sched_barrier(0);
}
#define LGKM0 do { asm volatile("s_waitcnt lgkmcnt(0)" ::: "memory"); \
                   __builtin_amdgcn_sched_barrier(0); } while (0)
#define VMCNT(n) asm volatile("s_waitcnt vmcnt(" #n ")" ::: "memory")

// ---- top-2 expert selection per batch (B=4, E=8) ----
__global__ void k_top2(const float* __restrict__ gv, int* __restrict__ idx) {
  int b = threadIdx.x;
  if (b < 4) {
    const float* g = gv + b * 8;
    int i1 = 0; float v1 = g[0];
    for (int e = 1; e < 8; ++e) if (g[e] > v1) { v1 = g[e]; i1 = e; }
    int i2 = -1; float v2 = -3.0e38f;
    for (int e = 0; e < 8; ++e) if (e != i1 && g[e] > v2) { v2 = g[e]; i2 = e; }
    idx[2 * b] = i1; idx[2 * b + 1] = i2;
  }
}

// ---- flat fp32 -> bf16 cast, vectorized ----
__global__ void k_cast(const float* __restrict__ in, u16* __restrict__ out, int n4) {
  int i = blockIdx.x * 256 + threadIdx.x;
  if (i < n4) {
    float4 v = ((const float4*)in)[i];
    ushort4 o = make_ushort4(f2bf(v.x), f2bf(v.y), f2bf(v.z), f2bf(v.w));
    ((ushort4*)out)[i] = o;
  }
}

// ---- 2D cast with zero padding: out[Ro x Co] <- in[Rs x Cs], pad = 0 ----
__global__ void k_cast2d(const float* __restrict__ in, u16* __restrict__ out,
                         int Rs, int Cs, int total4, int Co) {
  int i = blockIdx.x * 256 + threadIdx.x;
  if (i >= total4) return;
  size_t e0 = (size_t)i * 4;
  int c = (int)(e0 % Co);
  int r = (int)(e0 / Co);
  ushort4 o;
  if (r < Rs && c + 3 < Cs) {
    float4 v = *(const float4*)(in + (size_t)r * Cs + c);
    o = make_ushort4(f2bf(v.x), f2bf(v.y), f2bf(v.z), f2bf(v.w));
  } else {
    u16 a[4];
    #pragma unroll
    for (int k = 0; k < 4; ++k)
      a[k] = (r < Rs && c + k < Cs) ? f2bf(in[(size_t)r * Cs + c + k]) : (u16)0;
    o = make_ushort4(a[0], a[1], a[2], a[3]);
  }
  *(ushort4*)(out + e0) = o;
}

// ---- per-batch A^T panels: out[b][j][k] = src[e][k][r], bf16 ----
__global__ void k_aT(const float* __restrict__ A0, const float* __restrict__ A1,
                     const int* __restrict__ idx, u16* __restrict__ out,
                     int Kd, int jmax) {
  int t = blockIdx.x * 256 + threadIdx.x;
  if (t >= 4 * jmax * Kd) return;
  int h = t % Kd;
  int j = (t / Kd) % jmax;
  int b = t / (Kd * jmax);
  const float* src = (j >= 32) ? A1 : A0;
  int jj = j & 31;
  int e = idx[2 * b + ((jj >> 4) & 1)];
  int r = jj & 15;
  out[t] = f2bf(src[((size_t)e * Kd + h) * 16 + r]);
}

// ---- per-batch B_cat^T with zero pad rows: out[b][n][j], n < Nout ----
__global__ void k_bT(const float* __restrict__ Bsrc, const int* __restrict__ idx,
                     u16* __restrict__ out, int Nout, int Nsrc) {
  int t = blockIdx.x * 256 + threadIdx.x;
  if (t < 4 * Nout * 32) {
    int j = t & 31;
    int n = (t >> 5) % Nout;
    int b = t / (Nout * 32);
    int e = (j & 16) ? idx[2 * b + 1] : idx[2 * b];
    int r = j & 15;
    out[t] = (n < Nsrc) ? f2bf(Bsrc[((size_t)e * 16 + r) * Nsrc + n]) : (u16)0;
  }
}

// ---- skinny MFMA GEMM with split-K (A row-stride lda, BT row-stride K) ----
template <int N2>
__global__ __launch_bounds__(256) void k_skinny(
    const u16* __restrict__ A, const u16* __restrict__ BT,
    float* __restrict__ part, int M, int lda, int K, int total_iters,
    int iters_per_chunk) {
  __shared__ u16 sA[128 * 64];
  __shared__ u16 sB[N2 * 64];
  int nm = M >> 7;
  int bm = blockIdx.x % nm, chunk = blockIdx.x / nm;
  int m0 = bm << 7;
  int batch = m0 >> 11;
  int tid = threadIdx.x, lane = tid & 63, w = tid >> 6;
  int kb = chunk * iters_per_chunk;
  int ke = min(total_iters, kb + iters_per_chunk);

  const u16* Bb = BT + (size_t)batch * N2 * K;

  const u16* ga[4]; u16* la[4];
  #pragma unroll
  for (int t = 0; t < 4; ++t) {
    int cb = 4 * w + t;
    int q = cb * 64 + lane;
    int row = q >> 3;
    int c = (q & 7) ^ (row & 7);
    ga[t] = A + (size_t)(m0 + row) * lda + (size_t)kb * 64 + c * 8;
    la[t] = sA + cb * 512;
  }
  constexpr int nB = N2 / 32;
  const u16* gb[nB]; u16* lb[nB];
  #pragma unroll
  for (int t = 0; t < nB; ++t) {
    int cb = nB * w + t;
    int q = cb * 64 + lane;
    int row = q >> 3;
    int c = (q & 7) ^ (row & 7);
    gb[t] = Bb + (size_t)row * K + (size_t)kb * 64 + c * 8;
    lb[t] = sB + cb * 512;
  }

  f32x4 acc[2][N2 / 16] = {};
  for (int kt = kb; kt < ke; ++kt) {
    #pragma unroll
    for (int t = 0; t < 4; ++t) { g2l16(ga[t], la[t]); ga[t] += 64; }
    #pragma unroll
    for (int t = 0; t < nB; ++t) { g2l16(gb[t], lb[t]); gb[t] += 64; }
    __syncthreads();
    #pragma unroll
    for (int ks = 0; ks < 2; ++ks) {
      int cb0 = ks * 4 + (lane >> 4);
      bf16x8 af[2], bfr[N2 / 16];
      #pragma unroll
      for (int mi = 0; mi < 2; ++mi) {
        int row = 32 * w + mi * 16 + (lane & 15);
        af[mi] = *(const bf16x8*)(sA + (row * 8 + (cb0 ^ (row & 7))) * 8);
      }
      #pragma unroll
      for (int ni = 0; ni < N2 / 16; ++ni) {
        int row = ni * 16 + (lane & 15);
        bfr[ni] = *(const bf16x8*)(sB + (row * 8 + (cb0 ^ (row & 7))) * 8);
      }
      #pragma unroll
      for (int mi = 0; mi < 2; ++mi)
        #pragma unroll
        for (int ni = 0; ni < N2 / 16; ++ni)
          acc[mi][ni] = __builtin_amdgcn_mfma_f32_16x16x32_bf16(
              af[mi], bfr[ni], acc[mi][ni], 0, 0, 0);
    }
    __syncthreads();
  }

  int rb = (lane >> 4) * 4, cc = lane & 15;
  #pragma unroll
  for (int mi = 0; mi < 2; ++mi)
    #pragma unroll
    for (int ni = 0; ni < N2 / 16; ++ni)
      #pragma unroll
      for (int reg = 0; reg < 4; ++reg) {
        int gr = m0 + 32 * w + mi * 16 + rb + reg;
        int gc = ni * 16 + cc;
        part[((size_t)chunk * M + gr) * N2 + gc] = acc[mi][ni][reg];
      }
}

// ---- finalize split-K: out = bf16(2 * sum_chunks part) ----
__global__ void k_fin(const float* __restrict__ part, u16* __restrict__ out0,
                      u16* __restrict__ out1, int M, int N2, int nch) {
  int t = blockIdx.x * 256 + threadIdx.x;
  if (t >= M * N2) return;
  float s = 0.f;
  for (int c = 0; c < nch; ++c) s += part[(size_t)c * M * N2 + t];
  int j = t % N2, bs = t / N2;
  u16 v = f2bf(2.0f * s);
  if (N2 == 64) {
    if (j < 32) out0[(size_t)bs * 32 + j] = v;
    else        out1[(size_t)bs * 32 + (j - 32)] = v;
  } else {
    out0[(size_t)bs * 32 + j] = v;
  }
}

// ================= 256x256 8-phase counted-vmcnt GEMM =================
// BM=BN=256, BK=64, 512 threads (2x4 waves), per-wave C = 128x64 split into
// 4 phase-quadrants (mh,nh) in order (0,0),(0,1),(1,1),(1,0). LDS 128 KiB:
// 2 dbuf x (A 256x64 + B 256x64) bf16, XOR-swizzled via pre-swizzled global
// source. Staging runs 6 phases ahead (half-tile h staged at phase h-6);
// steady-state wait is vmcnt(4) once per K-tile (never 0 in main loop).
// Slot write->last-read margins (barrier-separated phases): A0 +2, A1 +1,
// B0 +1, B1 +4 -- all safe. Requires K%128==0 (kiters even, >=4), M%2048==0
// (batch tiles), N%256==0, grid = (M/256)*(N/256), grid%8==0.
__global__ __launch_bounds__(512, 2)
void k_gemm256(const u16* __restrict__ A, const u16* __restrict__ Bm,
               const u16* __restrict__ A2, const u16* __restrict__ B2,
               const u16* __restrict__ Gprev, void* __restrict__ Out,
               int N, int K, int mode) {
  __shared__ u16 lds[65536];  // 128 KiB
  int nt = N >> 8;
  int nm = gridDim.x / nt;
  int perx = nm >> 3;
  int xcd = blockIdx.x & 7;
  int v = blockIdx.x >> 3;
  int bn = v / perx;
  int bm = xcd * perx + (v - bn * perx);
  int m0 = bm << 8, n0 = bn << 8;
  int batch = m0 >> 11;

  int tid = threadIdx.x;
  int lane = tid & 63, w = tid >> 6;
  int wm = w >> 2, wn = w & 3;
  int g = lane >> 4, l7 = lane & 7, l15 = lane & 15;

  // staging source (pre-swizzled global address; LDS dest stays linear)
  int srow = w * 8 + (lane >> 3);
  int scol = ((lane & 7) ^ (lane >> 3)) * 8;
  const u16* pA = A + (size_t)(m0 + srow) * K + scol;
  const u16* pB = Bm + (size_t)(n0 + srow) * K + scol;

  uint32_t Lb = (uint32_t)(uint64_t)(&lds[0]);
  uint32_t aTh0 = (uint32_t)(wm * 8192 + l15 * 128 + ((g ^ l7) * 16));
  uint32_t aTh1 = aTh0 ^ 64;
  uint32_t bTh0 = (uint32_t)(wn * 4096 + l15 * 128 + ((g ^ l7) * 16));
  uint32_t bTh1 = bTh0 ^ 64;

  f32x4 acc[2][4][2][2] = {};
  bf16x8 af[4][2], bfr[2][2];

  int kiters = K >> 6;

#define STAGE_A(h1, jt_) do { \
    u16* _d = lds + (((jt_) & 1) << 14) + ((h1) * 8192) + (w << 9); \
    const u16* _s = pA + (size_t)((h1) * 128) * K + (((size_t)(jt_)) << 6); \
    g2l16(_s, _d); \
    g2l16(_s + (size_t)64 * K, _d + 4096); \
  } while (0)
#define STAGE_B(h1, jt_) do { \
    u16* _d = lds + 32768 + (((jt_) & 1) << 14) + ((h1) * 8192) + (w << 9); \
    const u16* _s = pB + (size_t)((h1) * 128) * K + (((size_t)(jt_)) << 6); \
    g2l16(_s, _d); \
    g2l16(_s + (size_t)64 * K, _d + 4096); \
  } while (0)
#define LDA(mh, bufb) do { \
    uint32_t _b = Lb + (bufb) + (mh) * 16384; \
    _Pragma("unroll") for (int mi = 0; mi < 4; ++mi) { \
      af[mi][0] = dsr(_b + aTh0 + mi * 2048); \
      af[mi][1] = dsr(_b + aTh1 + mi * 2048); \
    } } while (0)
#define LDB(nh, bufb) do { \
    uint32_t _b = Lb + 65536 + (bufb) + (nh) * 16384; \
    _Pragma("unroll") for (int ni = 0; ni < 2; ++ni) { \
      bfr[ni][0] = dsr(_b + bTh0 + ni * 2048); \
      bfr[ni][1] = dsr(_b + bTh1 + ni * 2048); \
    } } while (0)
#define MFMA_Q(mh, nh) do { \
    __builtin_amdgcn_s_setprio(1); \
    _Pragma("unroll") for (int ks = 0; ks < 2; ++ks) \
      _Pragma("unroll") for (int mi = 0; mi < 4; ++mi) \
        _Pragma("unroll") for (int ni = 0; ni < 2; ++ni) \
          acc[mh][mi][nh][ni] = __builtin_amdgcn_mfma_f32_16x16x32_bf16( \
              af[mi][ks], bfr[ni][ks], acc[mh][mi][nh][ni], 0, 0, 0); \
    __builtin_amdgcn_s_setprio(0); \
  } while (0)

  // prologue: tile0 {A0,A1,B0,B1}, tile1 {A0,A1}; allow tile1's A in flight
  STAGE_A(0, 0); STAGE_A(1, 0); STAGE_B(0, 0); STAGE_B(1, 0);
  STAGE_A(0, 1); STAGE_A(1, 1);
  VMCNT(4);
  barx();

  int jt = 0;
  for (; jt < kiters - 2; ++jt) {
    uint32_t bufb = (uint32_t)((jt & 1) << 15);
    // P0: quad(0,0)
    LDA(0, bufb); LDB(0, bufb);
    STAGE_B(0, jt + 1);
    barx(); LGKM0; MFMA_Q(0, 0); barx();
    // P1: quad(0,1)
    LDB(1, bufb);
    STAGE_B(1, jt + 1);
    barx(); LGKM0; MFMA_Q(0, 1); barx();
    // P2: quad(1,1)
    LDA(1, bufb);
    STAGE_A(0, jt + 2);
    barx(); LGKM0; MFMA_Q(1, 1); barx();
    // P3: quad(1,0)
    LDB(0, bufb);
    STAGE_A(1, jt + 2);
    VMCNT(4);
    barx(); LGKM0; MFMA_Q(1, 0); barx();
  }
  // tile kiters-2: stage last tile's B halves, then drain
  {
    uint32_t bufb = (uint32_t)((jt & 1) << 15);
    LDA(0, bufb); LDB(0, bufb);
    STAGE_B(0, kiters - 1);
    barx(); LGKM0; MFMA_Q(0, 0); barx();
    LDB(1, bufb);
    STAGE_B(1, kiters - 1);
    barx(); LGKM0; MFMA_Q(0, 1); barx();
    LDA(1, bufb);
    barx(); LGKM0; MFMA_Q(1, 1); barx();
    LDB(0, bufb);
    VMCNT(0);
    barx(); LGKM0; MFMA_Q(1, 0); barx();
  }
  // tile kiters-1: pure compute
  {
    uint32_t bufb = (uint32_t)(((kiters - 1) & 1) << 15);
    LDA(0, bufb); LDB(0, bufb); LGKM0; MFMA_Q(0, 0);
    LDB(1, bufb); LGKM0; MFMA_Q(0, 1);
    LDA(1, bufb); LGKM0; MFMA_Q(1, 1);
    LDB(0, bufb); LGKM0; MFMA_Q(1, 0);
  }

  // ---- LoRA extra K=32 step (A2: [M][32], B2: [batch][N][32]) ----
  {
    const u16* B2b = B2 + (size_t)batch * N * 32;
    int srow2 = w * 16 + (lane >> 2);
    int scol2 = ((lane & 3) ^ ((lane >> 2) & 3)) * 8;
    const u16* pA2 = A2 + (size_t)(m0 + srow2) * 32 + scol2;
    const u16* pB2 = B2b + (size_t)(n0 + srow2) * 32 + scol2;
    barx();  // all waves done reading K-loop LDS before overwrite of buffer0
    {
      u16* dA = lds + (w << 9);
      g2l16(pA2, dA); g2l16(pA2 + 4096, dA + 4096);
      u16* dB = lds + 32768 + (w << 9);
      g2l16(pB2, dB); g2l16(pB2 + 4096, dB + 4096);
    }
    VMCNT(0);
    barx();
    uint32_t c2 = (uint32_t)((g ^ (lane & 3)) * 16);
    bf16x8 af2[4], bf2[2];
    #pragma unroll
    for (int mh = 0; mh < 2; ++mh) {
      #pragma unroll
      for (int mi = 0; mi < 4; ++mi)
        af2[mi] = dsr(Lb + mh * 8192 + wm * 4096 + mi * 1024 + l15 * 64 + c2);
      #pragma unroll
      for (int nh = 0; nh < 2; ++nh) {
        bf2[0] = dsr(Lb + 65536 + nh * 8192 + wn * 2048 + l15 * 64 + c2);
        bf2[1] = dsr(Lb + 65536 + nh * 8192 + wn * 2048 + 1024 + l15 * 64 + c2);
        LGKM0;
        #pragma unroll
        for (int mi = 0; mi < 4; ++mi)
          #pragma unroll
          for (int ni = 0; ni < 2; ++ni)
            acc[mh][mi][nh][ni] = __builtin_amdgcn_mfma_f32_16x16x32_bf16(
                af2[mi], bf2[ni], acc[mh][mi][nh][ni], 0, 0, 0);
      }
    }
  }

  // ---- epilogue ----
  int rb = (lane >> 4) * 4, cc = lane & 15;
  #pragma unroll
  for (int mh = 0; mh < 2; ++mh)
    #pragma unroll
    for (int mi = 0; mi < 4; ++mi)
      #pragma unroll
      for (int nh = 0; nh < 2; ++nh)
        #pragma unroll
        for (int ni = 0; ni < 2; ++ni)
          #pragma unroll
          for (int reg = 0; reg < 4; ++reg) {
            int gr = m0 + mh * 128 + wm * 64 + mi * 16 + rb + reg;
            int gc = n0 + nh * 128 + wn * 32 + ni * 16 + cc;
            size_t pos = (size_t)gr * N + gc;
            float vv = acc[mh][mi][nh][ni][reg];
            if (mode == 0) {
              vv = vv / (1.f + __expf(-vv));
              ((u16*)Out)[pos] = f2bf(vv);
            } else if (mode == 1) {
              float gg = bf2f(Gprev[pos]);
              ((u16*)Out)[pos] = f2bf(gg * vv);
            } else {
              ((float*)Out)[pos] = vv;
            }
          }
#undef STAGE_A
#undef STAGE_B
#undef LDA
#undef LDB
#undef MFMA_Q
}

extern "C" void kernel_launch(void* const* d_in, const int* in_sizes, int n_in,
                              void* d_out, int out_size, void* d_ws, size_t ws_size,
                              hipStream_t stream) {
  const float* x  = (const float*)d_in[0];
  const float* gv = (const float*)d_in[1];
  const float* Wg = (const float*)d_in[2];
  const float* Ag = (const float*)d_in[3];
  const float* Bg = (const float*)d_in[4];
  const float* Wu = (const float*)d_in[5];
  const float* Au = (const float*)d_in[6];
  const float* Bu = (const float*)d_in[7];
  const float* Wd = (const float*)d_in[8];
  const float* Ad = (const float*)d_in[9];
  const float* Bd = (const float*)d_in[10];
  float* out = (float*)d_out;

  // N padded 5504 -> 5632 (22*256) so the 256-tile GEMM covers gate/up N and
  // down K exactly; all pads zeroed so padded contributions are exactly 0.
  char* ws = (char*)d_ws;
  size_t off = 0;
  auto alloc = [&](size_t bytes) -> void* {
    void* p = ws + off;
    off = (off + bytes + 255) & ~(size_t)255;
    return p;
  };
  int* idx  = (int*)alloc(32);
  u16* xb   = (u16*)alloc((size_t)8192 * 2048 * 2);
  u16* Wgb  = (u16*)alloc((size_t)5632 * 2048 * 2);
  u16* Wub  = (u16*)alloc((size_t)5632 * 2048 * 2);
  u16* xag  = (u16*)alloc((size_t)8192 * 32 * 2);
  u16* xau  = (u16*)alloc((size_t)8192 * 32 * 2);
  u16* ha   = (u16*)alloc((size_t)8192 * 32 * 2);
  u16* BgT  = (u16*)alloc((size_t)4 * 5632 * 32 * 2);
  u16* BuT  = (u16*)alloc((size_t)4 * 5632 * 32 * 2);
  u16* BdT  = (u16*)alloc((size_t)4 * 2048 * 32 * 2);
  u16* AxT  = (u16*)alloc((size_t)4 * 64 * 2048 * 2);
  u16* AdT  = (u16*)alloc((size_t)4 * 32 * 5504 * 2);
  u16* gbuf = (u16*)alloc((size_t)8192 * 5632 * 2);
  if (off > ws_size) return;

  u16* Wdb = Wub;                  // alias: Wub dead after up GEMM
  float* part_xa = (float*)gbuf;   // dead region until gate GEMM
  float* part_ha = (float*)Wgb;    // dead region after gate GEMM

  k_top2<<<1, 64, 0, stream>>>(gv, idx);
  k_cast<<<16384, 256, 0, stream>>>(x, xb, 4194304);
  k_cast2d<<<11264, 256, 0, stream>>>(Wg, Wgb, 5504, 2048, 2883584, 2048);
  k_cast2d<<<11264, 256, 0, stream>>>(Wu, Wub, 5504, 2048, 2883584, 2048);
  k_aT<<<2048, 256, 0, stream>>>(Ag, Au, idx, AxT, 2048, 64);
  k_aT<<<2752, 256, 0, stream>>>(Ad, Ad, idx, AdT, 5504, 32);
  k_bT<<<2816, 256, 0, stream>>>(Bg, idx, BgT, 5632, 5504);
  k_bT<<<2816, 256, 0, stream>>>(Bu, idx, BuT, 5632, 5504);
  k_bT<<<1024, 256, 0, stream>>>(Bd, idx, BdT, 2048, 2048);

  // xa: [8192 x 64] = xb @ AxT^T, split-K 4 chunks (K=2048)
  k_skinny<64><<<64 * 4, 256, 0, stream>>>(xb, AxT, part_xa, 8192, 2048, 2048, 32, 8);
  k_fin<<<2048, 256, 0, stream>>>(part_xa, xag, xau, 8192, 64, 4);

  // gate: silu(x@Wg^T + lora) -> gbuf (bf16, N=5632 padded)
  k_gemm256<<<32 * 22, 512, 0, stream>>>(xb, Wgb, xag, BgT, (const u16*)nullptr,
                                         gbuf, 5632, 2048, 0);
  // up: h = silu_gate * (x@Wu^T + lora) -> gbuf in place
  k_gemm256<<<32 * 22, 512, 0, stream>>>(xb, Wub, xau, BuT, gbuf,
                                         gbuf, 5632, 2048, 1);

  // Wd cast into aliased Wub region (stream-ordered after up GEMM)
  k_cast2d<<<11264, 256, 0, stream>>>(Wd, Wdb, 2048, 5504, 2883584, 5632);

  // ha: [8192 x 32] = h @ AdT^T, split-K 4 chunks (K=5504, lda=5632)
  k_skinny<32><<<64 * 4, 256, 0, stream>>>(gbuf, AdT, part_ha, 8192, 5632, 5504, 86, 22);
  k_fin<<<1024, 256, 0, stream>>>(part_ha, ha, ha, 8192, 32, 4);

  // down: out = h@Wd^T + lora (fp32), K padded to 5632 (pads are zero)
  k_gemm256<<<32 * 8, 512, 0, stream>>>(gbuf, Wdb, ha, BdT, (const u16*)nullptr,
                                        out, 2048, 5632, 2);
}

// Round 2
// 900.355 us; speedup vs baseline: 1.0136x; 1.0136x over previous
//
#include <hip/hip_runtime.h>
#include <stdint.h>

typedef unsigned short u16;
typedef __bf16 bf16x8 __attribute__((ext_vector_type(8)));
typedef float f32x4 __attribute__((ext_vector_type(4)));

#define AS1 __attribute__((address_space(1)))
#define AS3 __attribute__((address_space(3)))

__device__ __forceinline__ void g2l16(const void* g, void* l) {
  __builtin_amdgcn_global_load_lds((AS1 void*)(void*)g, (AS3 void*)l, 16, 0, 0);
}

__device__ __forceinline__ u16 f2bf(float f) {
  union { float f; uint32_t u; } v; v.f = f;
  return (u16)((v.u + 0x7fffu + ((v.u >> 16) & 1u)) >> 16);
}
__device__ __forceinline__ float bf2f(u16 b) {
  union { uint32_t u; float f; } v; v.u = ((uint32_t)b) << 16;
  return v.f;
}

// inline-asm ds_read with compile-time offset immediate
template <int OFF>
__device__ __forceinline__ bf16x8 dsrO(uint32_t a) {
  bf16x8 r;
  asm volatile("ds_read_b128 %0, %1 offset:%2" : "=v"(r) : "v"(a), "n"(OFF));
  return r;
}
__device__ __forceinline__ bf16x8 dsr(uint32_t a) {
  bf16x8 r;
  asm volatile("ds_read_b128 %0, %1" : "=v"(r) : "v"(a));
  return r;
}
__device__ __forceinline__ void barx() {
  __builtin_amdgcn_sched_barrier(0);
  __builtin_amdgcn_s_barrier();
  __builtin_amdgcn_sched_barrier(0);
}
#define LGKM0 do { asm volatile("s_waitcnt lgkmcnt(0)" ::: "memory"); \
                   __builtin_amdgcn_sched_barrier(0); } while (0)
#define VMCNT(n) asm volatile("s_waitcnt vmcnt(" #n ")" ::: "memory")

// ---- top-2 expert selection per batch (B=4, E=8) ----
__global__ void k_top2(const float* __restrict__ gv, int* __restrict__ idx) {
  int b = threadIdx.x;
  if (b < 4) {
    const float* g = gv + b * 8;
    int i1 = 0; float v1 = g[0];
    for (int e = 1; e < 8; ++e) if (g[e] > v1) { v1 = g[e]; i1 = e; }
    int i2 = -1; float v2 = -3.0e38f;
    for (int e = 0; e < 8; ++e) if (e != i1 && g[e] > v2) { v2 = g[e]; i2 = e; }
    idx[2 * b] = i1; idx[2 * b + 1] = i2;
  }
}

// ---- flat fp32 -> bf16 cast, vectorized ----
__global__ void k_cast(const float* __restrict__ in, u16* __restrict__ out, int n4) {
  int i = blockIdx.x * 256 + threadIdx.x;
  if (i < n4) {
    float4 v = ((const float4*)in)[i];
    ushort4 o = make_ushort4(f2bf(v.x), f2bf(v.y), f2bf(v.z), f2bf(v.w));
    ((ushort4*)out)[i] = o;
  }
}

// ---- 2D cast with zero padding: out[Ro x Co] <- in[Rs x Cs], pad = 0 ----
__global__ void k_cast2d(const float* __restrict__ in, u16* __restrict__ out,
                         int Rs, int Cs, int total4, int Co) {
  int i = blockIdx.x * 256 + threadIdx.x;
  if (i >= total4) return;
  size_t e0 = (size_t)i * 4;
  int c = (int)(e0 % Co);
  int r = (int)(e0 / Co);
  ushort4 o;
  if (r < Rs && c + 3 < Cs) {
    float4 v = *(const float4*)(in + (size_t)r * Cs + c);
    o = make_ushort4(f2bf(v.x), f2bf(v.y), f2bf(v.z), f2bf(v.w));
  } else {
    u16 a[4];
    #pragma unroll
    for (int k = 0; k < 4; ++k)
      a[k] = (r < Rs && c + k < Cs) ? f2bf(in[(size_t)r * Cs + c + k]) : (u16)0;
    o = make_ushort4(a[0], a[1], a[2], a[3]);
  }
  *(ushort4*)(out + e0) = o;
}

// ---- per-batch A^T panels: out[b][j][k] = src[e][k][r], bf16 ----
__global__ void k_aT(const float* __restrict__ A0, const float* __restrict__ A1,
                     const int* __restrict__ idx, u16* __restrict__ out,
                     int Kd, int jmax) {
  int t = blockIdx.x * 256 + threadIdx.x;
  if (t >= 4 * jmax * Kd) return;
  int h = t % Kd;
  int j = (t / Kd) % jmax;
  int b = t / (Kd * jmax);
  const float* src = (j >= 32) ? A1 : A0;
  int jj = j & 31;
  int e = idx[2 * b + ((jj >> 4) & 1)];
  int r = jj & 15;
  out[t] = f2bf(src[((size_t)e * Kd + h) * 16 + r]);
}

// ---- per-batch B_cat^T with zero pad rows: out[b][n][j], n < Nout ----
__global__ void k_bT(const float* __restrict__ Bsrc, const int* __restrict__ idx,
                     u16* __restrict__ out, int Nout, int Nsrc) {
  int t = blockIdx.x * 256 + threadIdx.x;
  if (t < 4 * Nout * 32) {
    int j = t & 31;
    int n = (t >> 5) % Nout;
    int b = t / (Nout * 32);
    int e = (j & 16) ? idx[2 * b + 1] : idx[2 * b];
    int r = j & 15;
    out[t] = (n < Nsrc) ? f2bf(Bsrc[((size_t)e * 16 + r) * Nsrc + n]) : (u16)0;
  }
}

// ---- skinny MFMA GEMM with split-K (A row-stride lda, BT row-stride K) ----
template <int N2>
__global__ __launch_bounds__(256) void k_skinny(
    const u16* __restrict__ A, const u16* __restrict__ BT,
    float* __restrict__ part, int M, int lda, int K, int total_iters,
    int iters_per_chunk) {
  __shared__ u16 sA[128 * 64];
  __shared__ u16 sB[N2 * 64];
  int nm = M >> 7;
  int bm = blockIdx.x % nm, chunk = blockIdx.x / nm;
  int m0 = bm << 7;
  int batch = m0 >> 11;
  int tid = threadIdx.x, lane = tid & 63, w = tid >> 6;
  int kb = chunk * iters_per_chunk;
  int ke = min(total_iters, kb + iters_per_chunk);

  const u16* Bb = BT + (size_t)batch * N2 * K;

  const u16* ga[4]; u16* la[4];
  #pragma unroll
  for (int t = 0; t < 4; ++t) {
    int cb = 4 * w + t;
    int q = cb * 64 + lane;
    int row = q >> 3;
    int c = (q & 7) ^ (row & 7);
    ga[t] = A + (size_t)(m0 + row) * lda + (size_t)kb * 64 + c * 8;
    la[t] = sA + cb * 512;
  }
  constexpr int nB = N2 / 32;
  const u16* gb[nB]; u16* lb[nB];
  #pragma unroll
  for (int t = 0; t < nB; ++t) {
    int cb = nB * w + t;
    int q = cb * 64 + lane;
    int row = q >> 3;
    int c = (q & 7) ^ (row & 7);
    gb[t] = Bb + (size_t)row * K + (size_t)kb * 64 + c * 8;
    lb[t] = sB + cb * 512;
  }

  f32x4 acc[2][N2 / 16] = {};
  for (int kt = kb; kt < ke; ++kt) {
    #pragma unroll
    for (int t = 0; t < 4; ++t) { g2l16(ga[t], la[t]); ga[t] += 64; }
    #pragma unroll
    for (int t = 0; t < nB; ++t) { g2l16(gb[t], lb[t]); gb[t] += 64; }
    __syncthreads();
    #pragma unroll
    for (int ks = 0; ks < 2; ++ks) {
      int cb0 = ks * 4 + (lane >> 4);
      bf16x8 af[2], bfr[N2 / 16];
      #pragma unroll
      for (int mi = 0; mi < 2; ++mi) {
        int row = 32 * w + mi * 16 + (lane & 15);
        af[mi] = *(const bf16x8*)(sA + (row * 8 + (cb0 ^ (row & 7))) * 8);
      }
      #pragma unroll
      for (int ni = 0; ni < N2 / 16; ++ni) {
        int row = ni * 16 + (lane & 15);
        bfr[ni] = *(const bf16x8*)(sB + (row * 8 + (cb0 ^ (row & 7))) * 8);
      }
      #pragma unroll
      for (int mi = 0; mi < 2; ++mi)
        #pragma unroll
        for (int ni = 0; ni < N2 / 16; ++ni)
          acc[mi][ni] = __builtin_amdgcn_mfma_f32_16x16x32_bf16(
              af[mi], bfr[ni], acc[mi][ni], 0, 0, 0);
    }
    __syncthreads();
  }

  int rb = (lane >> 4) * 4, cc = lane & 15;
  #pragma unroll
  for (int mi = 0; mi < 2; ++mi)
    #pragma unroll
    for (int ni = 0; ni < N2 / 16; ++ni)
      #pragma unroll
      for (int reg = 0; reg < 4; ++reg) {
        int gr = m0 + 32 * w + mi * 16 + rb + reg;
        int gc = ni * 16 + cc;
        part[((size_t)chunk * M + gr) * N2 + gc] = acc[mi][ni][reg];
      }
}

// ---- finalize split-K: out = bf16(2 * sum_chunks part) ----
__global__ void k_fin(const float* __restrict__ part, u16* __restrict__ out0,
                      u16* __restrict__ out1, int M, int N2, int nch) {
  int t = blockIdx.x * 256 + threadIdx.x;
  if (t >= M * N2) return;
  float s = 0.f;
  for (int c = 0; c < nch; ++c) s += part[(size_t)c * M * N2 + t];
  int j = t % N2, bs = t / N2;
  u16 v = f2bf(2.0f * s);
  if (N2 == 64) {
    if (j < 32) out0[(size_t)bs * 32 + j] = v;
    else        out1[(size_t)bs * 32 + (j - 32)] = v;
  } else {
    out0[(size_t)bs * 32 + j] = v;
  }
}

// ================= 256x256 8-phase counted-vmcnt GEMM (v2) =================
// BM=BN=256, BK=64, 512 threads (2x4 waves), per-wave C = 128x64, quadrant
// order (0,0),(0,1),(1,1),(1,0). B0 fragment cached in regs across the tile
// (P3 has zero ds_reads). Stagger per tile jt: P0 stages B1(jt+1), P1 A0(jt+2),
// P2 B0(jt+2), P3 A1(jt+2) + vmcnt(6) AFTER P3's MFMA -> 3 half-tiles in
// flight, tile jt+1 fully landed at the tile boundary barrier. Same-buffer
// write hazards (jt+2 halves): A0 read P0/staged P1, B0 read P0/staged P2,
// A1 read P2/staged P3 -- all separated by >=1 barrier. 2 K-tiles unrolled so
// the LDS buffer select is a compile-time ds_read offset immediate.
// Requires K%128==0, M%2048==0, N%256==0, grid=(M/256)*(N/256), grid%8==0.
__global__ __launch_bounds__(512, 2)
void k_gemm256(const u16* __restrict__ A, const u16* __restrict__ Bm,
               const u16* __restrict__ A2, const u16* __restrict__ B2,
               const u16* __restrict__ Gprev, void* __restrict__ Out,
               int N, int K, int mode) {
  __shared__ u16 lds[65536];  // 128 KiB: A[2][32KB] @0, B[2][32KB] @65536B
  int nt = N >> 8;
  int nm = gridDim.x / nt;
  int perx = nm >> 3;
  int xcd = blockIdx.x & 7;
  int v = blockIdx.x >> 3;
  int bn = v / perx;
  int bm = xcd * perx + (v - bn * perx);
  int m0 = bm << 8, n0 = bn << 8;
  int batch = m0 >> 11;

  int tid = threadIdx.x;
  int lane = tid & 63, w = tid >> 6;
  int wm = w >> 2, wn = w & 3;
  int g = lane >> 4, l7 = lane & 7, l15 = lane & 15;

  // staging source (pre-swizzled global address; LDS dest stays linear)
  int srow = w * 8 + (lane >> 3);
  int scol = ((lane & 7) ^ (lane >> 3)) * 8;
  const u16* pA = A + (size_t)(m0 + srow) * K + scol;
  const u16* pB = Bm + (size_t)(n0 + srow) * K + scol;

  uint32_t Lb = (uint32_t)(uint64_t)(&lds[0]);
  uint32_t bA0 = Lb + (uint32_t)(wm * 8192 + l15 * 128 + ((g ^ l7) * 16));
  uint32_t bA1 = bA0 ^ 64;
  uint32_t bB0 = Lb + 65536u + (uint32_t)(wn * 4096 + l15 * 128 + ((g ^ l7) * 16));
  uint32_t bB1 = bB0 ^ 64;

  f32x4 acc[2][4][2][2] = {};
  bf16x8 af[4][2], b0f[2][2], b1f[2][2];

  int kiters = K >> 6;

#define STAGE_A(h1, jt_) do { \
    u16* _d = lds + (((jt_) & 1) << 14) + ((h1) * 8192) + (w << 9); \
    const u16* _s = pA + (size_t)((h1) * 128) * K + (((size_t)(jt_)) << 6); \
    g2l16(_s, _d); \
    g2l16(_s + (size_t)64 * K, _d + 4096); \
  } while (0)
#define STAGE_B(h1, jt_) do { \
    u16* _d = lds + 32768 + (((jt_) & 1) << 14) + ((h1) * 8192) + (w << 9); \
    const u16* _s = pB + (size_t)((h1) * 128) * K + (((size_t)(jt_)) << 6); \
    g2l16(_s, _d); \
    g2l16(_s + (size_t)64 * K, _d + 4096); \
  } while (0)
#define LDA_IMM(mh, BUF) do { \
    af[0][0] = dsrO<(BUF)*32768 + (mh)*16384 + 0>(bA0); \
    af[0][1] = dsrO<(BUF)*32768 + (mh)*16384 + 0>(bA1); \
    af[1][0] = dsrO<(BUF)*32768 + (mh)*16384 + 2048>(bA0); \
    af[1][1] = dsrO<(BUF)*32768 + (mh)*16384 + 2048>(bA1); \
    af[2][0] = dsrO<(BUF)*32768 + (mh)*16384 + 4096>(bA0); \
    af[2][1] = dsrO<(BUF)*32768 + (mh)*16384 + 4096>(bA1); \
    af[3][0] = dsrO<(BUF)*32768 + (mh)*16384 + 6144>(bA0); \
    af[3][1] = dsrO<(BUF)*32768 + (mh)*16384 + 6144>(bA1); \
  } while (0)
#define LDB_IMM(dst, nh, BUF) do { \
    dst[0][0] = dsrO<(BUF)*32768 + (nh)*16384 + 0>(bB0); \
    dst[0][1] = dsrO<(BUF)*32768 + (nh)*16384 + 0>(bB1); \
    dst[1][0] = dsrO<(BUF)*32768 + (nh)*16384 + 2048>(bB0); \
    dst[1][1] = dsrO<(BUF)*32768 + (nh)*16384 + 2048>(bB1); \
  } while (0)
#define MFMA_Q(mh, nh, BF) do { \
    __builtin_amdgcn_s_setprio(1); \
    _Pragma("unroll") for (int ks = 0; ks < 2; ++ks) \
      _Pragma("unroll") for (int mi = 0; mi < 4; ++mi) \
        _Pragma("unroll") for (int ni = 0; ni < 2; ++ni) \
          acc[mh][mi][nh][ni] = __builtin_amdgcn_mfma_f32_16x16x32_bf16( \
              af[mi][ks], BF[ni][ks], acc[mh][mi][nh][ni], 0, 0, 0); \
    __builtin_amdgcn_s_setprio(0); \
  } while (0)

// one steady-state K-tile; BUF is a literal 0/1
#define TILE_BODY(BUF, jt_) do { \
    /* P0: read A0+B0, stage B1(jt+1) */ \
    LDA_IMM(0, BUF); \
    LDB_IMM(b0f, 0, BUF); \
    STAGE_B(1, (jt_) + 1); \
    barx(); LGKM0; MFMA_Q(0, 0, b0f); barx(); \
    /* P1: read B1, stage A0(jt+2) */ \
    LDB_IMM(b1f, 1, BUF); \
    STAGE_A(0, (jt_) + 2); \
    barx(); LGKM0; MFMA_Q(0, 1, b1f); barx(); \
    /* P2: read A1, stage B0(jt+2) */ \
    LDA_IMM(1, BUF); \
    STAGE_B(0, (jt_) + 2); \
    barx(); LGKM0; MFMA_Q(1, 1, b1f); barx(); \
    /* P3: no reads; stage A1(jt+2); vmcnt hidden under MFMA */ \
    STAGE_A(1, (jt_) + 2); \
    MFMA_Q(1, 0, b0f); \
    VMCNT(6); \
    barx(); \
  } while (0)

  // prologue: tile0 fully, then A0,B0,A1 of tile1 (3 half-tiles in flight)
  STAGE_A(0, 0); STAGE_A(1, 0); STAGE_B(0, 0); STAGE_B(1, 0);
  STAGE_A(0, 1); STAGE_B(0, 1); STAGE_A(1, 1);
  VMCNT(6);
  barx();

  for (int jt = 0; jt + 3 < kiters; jt += 2) {
    TILE_BODY(0, jt);
    TILE_BODY(1, jt + 1);
  }
  // tile kiters-2 (BUF=0): stage only B1(last), drain at end
  {
    LDA_IMM(0, 0);
    LDB_IMM(b0f, 0, 0);
    STAGE_B(1, kiters - 1);
    barx(); LGKM0; MFMA_Q(0, 0, b0f); barx();
    LDB_IMM(b1f, 1, 0);
    barx(); LGKM0; MFMA_Q(0, 1, b1f); barx();
    LDA_IMM(1, 0);
    barx(); LGKM0; MFMA_Q(1, 1, b1f); barx();
    MFMA_Q(1, 0, b0f);
    VMCNT(0);
    barx();
  }
  // tile kiters-1 (BUF=1): pure compute, no barriers
  {
    LDA_IMM(0, 1);
    LDB_IMM(b0f, 0, 1);
    LGKM0; MFMA_Q(0, 0, b0f);
    LDB_IMM(b1f, 1, 1);
    LGKM0; MFMA_Q(0, 1, b1f);
    LDA_IMM(1, 1);
    LGKM0; MFMA_Q(1, 1, b1f);
    MFMA_Q(1, 0, b0f);
  }

  // ---- LoRA extra K=32 step (A2: [M][32], B2: [batch][N][32]) ----
  {
    const u16* B2b = B2 + (size_t)batch * N * 32;
    int srow2 = w * 16 + (lane >> 2);
    int scol2 = ((lane & 3) ^ ((lane >> 2) & 3)) * 8;
    const u16* pA2 = A2 + (size_t)(m0 + srow2) * 32 + scol2;
    const u16* pB2 = B2b + (size_t)(n0 + srow2) * 32 + scol2;
    barx();  // all waves done reading K-loop LDS before overwrite of buffer0
    {
      u16* dA = lds + (w << 9);
      g2l16(pA2, dA); g2l16(pA2 + 4096, dA + 4096);
      u16* dB = lds + 32768 + (w << 9);
      g2l16(pB2, dB); g2l16(pB2 + 4096, dB + 4096);
    }
    VMCNT(0);
    barx();
    uint32_t c2 = (uint32_t)((g ^ (lane & 3)) * 16);
    bf16x8 af2[4], bf2[2];
    #pragma unroll
    for (int mh = 0; mh < 2; ++mh) {
      #pragma unroll
      for (int mi = 0; mi < 4; ++mi)
        af2[mi] = dsr(Lb + mh * 8192 + wm * 4096 + mi * 1024 + l15 * 64 + c2);
      #pragma unroll
      for (int nh = 0; nh < 2; ++nh) {
        bf2[0] = dsr(Lb + 65536 + nh * 8192 + wn * 2048 + l15 * 64 + c2);
        bf2[1] = dsr(Lb + 65536 + nh * 8192 + wn * 2048 + 1024 + l15 * 64 + c2);
        LGKM0;
        #pragma unroll
        for (int mi = 0; mi < 4; ++mi)
          #pragma unroll
          for (int ni = 0; ni < 2; ++ni)
            acc[mh][mi][nh][ni] = __builtin_amdgcn_mfma_f32_16x16x32_bf16(
                af2[mi], bf2[ni], acc[mh][mi][nh][ni], 0, 0, 0);
      }
    }
  }

  // ---- epilogue ----
  int rb = (lane >> 4) * 4, cc = lane & 15;
  #pragma unroll
  for (int mh = 0; mh < 2; ++mh)
    #pragma unroll
    for (int mi = 0; mi < 4; ++mi)
      #pragma unroll
      for (int nh = 0; nh < 2; ++nh)
        #pragma unroll
        for (int ni = 0; ni < 2; ++ni)
          #pragma unroll
          for (int reg = 0; reg < 4; ++reg) {
            int gr = m0 + mh * 128 + wm * 64 + mi * 16 + rb + reg;
            int gc = n0 + nh * 128 + wn * 32 + ni * 16 + cc;
            size_t pos = (size_t)gr * N + gc;
            float vv = acc[mh][mi][nh][ni][reg];
            if (mode == 0) {
              vv = vv / (1.f + __expf(-vv));
              ((u16*)Out)[pos] = f2bf(vv);
            } else if (mode == 1) {
              float gg = bf2f(Gprev[pos]);
              ((u16*)Out)[pos] = f2bf(gg * vv);
            } else {
              ((float*)Out)[pos] = vv;
            }
          }
#undef STAGE_A
#undef STAGE_B
#undef LDA_IMM
#undef LDB_IMM
#undef MFMA_Q
#undef TILE_BODY
}

extern "C" void kernel_launch(void* const* d_in, const int* in_sizes, int n_in,
                              void* d_out, int out_size, void* d_ws, size_t ws_size,
                              hipStream_t stream) {
  const float* x  = (const float*)d_in[0];
  const float* gv = (const float*)d_in[1];
  const float* Wg = (const float*)d_in[2];
  const float* Ag = (const float*)d_in[3];
  const float* Bg = (const float*)d_in[4];
  const float* Wu = (const float*)d_in[5];
  const float* Au = (const float*)d_in[6];
  const float* Bu = (const float*)d_in[7];
  const float* Wd = (const float*)d_in[8];
  const float* Ad = (const float*)d_in[9];
  const float* Bd = (const float*)d_in[10];
  float* out = (float*)d_out;

  // N padded 5504 -> 5632 (22*256) so the 256-tile GEMM covers gate/up N and
  // down K exactly; all pads zeroed so padded contributions are exactly 0.
  char* ws = (char*)d_ws;
  size_t off = 0;
  auto alloc = [&](size_t bytes) -> void* {
    void* p = ws + off;
    off = (off + bytes + 255) & ~(size_t)255;
    return p;
  };
  int* idx  = (int*)alloc(32);
  u16* xb   = (u16*)alloc((size_t)8192 * 2048 * 2);
  u16* Wgb  = (u16*)alloc((size_t)5632 * 2048 * 2);
  u16* Wub  = (u16*)alloc((size_t)5632 * 2048 * 2);
  u16* xag  = (u16*)alloc((size_t)8192 * 32 * 2);
  u16* xau  = (u16*)alloc((size_t)8192 * 32 * 2);
  u16* ha   = (u16*)alloc((size_t)8192 * 32 * 2);
  u16* BgT  = (u16*)alloc((size_t)4 * 5632 * 32 * 2);
  u16* BuT  = (u16*)alloc((size_t)4 * 5632 * 32 * 2);
  u16* BdT  = (u16*)alloc((size_t)4 * 2048 * 32 * 2);
  u16* AxT  = (u16*)alloc((size_t)4 * 64 * 2048 * 2);
  u16* AdT  = (u16*)alloc((size_t)4 * 32 * 5504 * 2);
  u16* gbuf = (u16*)alloc((size_t)8192 * 5632 * 2);
  if (off > ws_size) return;

  u16* Wdb = Wub;                  // alias: Wub dead after up GEMM
  float* part_xa = (float*)gbuf;   // dead region until gate GEMM
  float* part_ha = (float*)Wgb;    // dead region after gate GEMM

  k_top2<<<1, 64, 0, stream>>>(gv, idx);
  k_cast<<<16384, 256, 0, stream>>>(x, xb, 4194304);
  k_cast2d<<<11264, 256, 0, stream>>>(Wg, Wgb, 5504, 2048, 2883584, 2048);
  k_cast2d<<<11264, 256, 0, stream>>>(Wu, Wub, 5504, 2048, 2883584, 2048);
  k_aT<<<2048, 256, 0, stream>>>(Ag, Au, idx, AxT, 2048, 64);
  k_aT<<<2752, 256, 0, stream>>>(Ad, Ad, idx, AdT, 5504, 32);
  k_bT<<<2816, 256, 0, stream>>>(Bg, idx, BgT, 5632, 5504);
  k_bT<<<2816, 256, 0, stream>>>(Bu, idx, BuT, 5632, 5504);
  k_bT<<<1024, 256, 0, stream>>>(Bd, idx, BdT, 2048, 2048);

  // xa: [8192 x 64] = xb @ AxT^T, split-K 4 chunks (K=2048)
  k_skinny<64><<<64 * 4, 256, 0, stream>>>(xb, AxT, part_xa, 8192, 2048, 2048, 32, 8);
  k_fin<<<2048, 256, 0, stream>>>(part_xa, xag, xau, 8192, 64, 4);

  // gate: silu(x@Wg^T + lora) -> gbuf (bf16, N=5632 padded)
  k_gemm256<<<32 * 22, 512, 0, stream>>>(xb, Wgb, xag, BgT, (const u16*)nullptr,
                                         gbuf, 5632, 2048, 0);
  // up: h = silu_gate * (x@Wu^T + lora) -> gbuf in place
  k_gemm256<<<32 * 22, 512, 0, stream>>>(xb, Wub, xau, BuT, gbuf,
                                         gbuf, 5632, 2048, 1);

  // Wd cast into aliased Wub region (stream-ordered after up GEMM)
  k_cast2d<<<11264, 256, 0, stream>>>(Wd, Wdb, 2048, 5504, 2883584, 5632);

  // ha: [8192 x 32] = h @ AdT^T, split-K 4 chunks (K=5504, lda=5632)
  k_skinny<32><<<64 * 4, 256, 0, stream>>>(gbuf, AdT, part_ha, 8192, 5632, 5504, 86, 22);
  k_fin<<<1024, 256, 0, stream>>>(part_ha, ha, ha, 8192, 32, 4);

  // down: out = h@Wd^T + lora (fp32), K padded to 5632 (pads are zero)
  k_gemm256<<<32 * 8, 512, 0, stream>>>(gbuf, Wdb, ha, BdT, (const u16*)nullptr,
                                        out, 2048, 5632, 2);
}

// Round 3
// 818.547 us; speedup vs baseline: 1.1149x; 1.0999x over previous
//
#include <hip/hip_runtime.h>
#include <stdint.h>

typedef unsigned short u16;
typedef __bf16 bf16x8 __attribute__((ext_vector_type(8)));
typedef float f32x4 __attribute__((ext_vector_type(4)));

#define AS1 __attribute__((address_space(1)))
#define AS3 __attribute__((address_space(3)))

__device__ __forceinline__ void g2l16(const void* g, void* l) {
  __builtin_amdgcn_global_load_lds((AS1 void*)(void*)g, (AS3 void*)l, 16, 0, 0);
}

__device__ __forceinline__ u16 f2bf(float f) {
  union { float f; uint32_t u; } v; v.f = f;
  return (u16)((v.u + 0x7fffu + ((v.u >> 16) & 1u)) >> 16);
}
__device__ __forceinline__ float bf2f(u16 b) {
  union { uint32_t u; float f; } v; v.u = ((uint32_t)b) << 16;
  return v.f;
}

// ---- top-2 expert selection per batch (B=4, E=8) ----
__global__ void k_top2(const float* __restrict__ gv, int* __restrict__ idx) {
  int b = threadIdx.x;
  if (b < 4) {
    const float* g = gv + b * 8;
    int i1 = 0; float v1 = g[0];
    for (int e = 1; e < 8; ++e) if (g[e] > v1) { v1 = g[e]; i1 = e; }
    int i2 = -1; float v2 = -3.0e38f;
    for (int e = 0; e < 8; ++e) if (e != i1 && g[e] > v2) { v2 = g[e]; i2 = e; }
    idx[2 * b] = i1; idx[2 * b + 1] = i2;
  }
}

// ---- fp32 -> bf16 cast, vectorized ----
__global__ void k_cast(const float* __restrict__ in, u16* __restrict__ out, int n4) {
  int i = blockIdx.x * 256 + threadIdx.x;
  if (i < n4) {
    float4 v = ((const float4*)in)[i];
    ushort4 o = make_ushort4(f2bf(v.x), f2bf(v.y), f2bf(v.z), f2bf(v.w));
    ((ushort4*)out)[i] = o;
  }
}

// ---- per-batch A^T panels: out[b][j][k] = src[e][k][r], bf16 ----
__global__ void k_aT(const float* __restrict__ A0, const float* __restrict__ A1,
                     const int* __restrict__ idx, u16* __restrict__ out,
                     int Kd, int jmax) {
  int t = blockIdx.x * 256 + threadIdx.x;
  if (t >= 4 * jmax * Kd) return;
  int h = t % Kd;
  int j = (t / Kd) % jmax;
  int b = t / (Kd * jmax);
  const float* src = (j >= 32) ? A1 : A0;
  int jj = j & 31;
  int e = idx[2 * b + ((jj >> 4) & 1)];
  int r = jj & 15;
  out[t] = f2bf(src[((size_t)e * Kd + h) * 16 + r]);
}

// ---- build per-batch B_cat^T: out[b][n][j] = B[e(b, j>=16)][j&15][n], bf16 ----
__global__ void k_bT(const float* __restrict__ Bsrc, const int* __restrict__ idx,
                     u16* __restrict__ out, int N) {
  int t = blockIdx.x * 256 + threadIdx.x;
  if (t < 4 * N * 32) {
    int j = t & 31;
    int n = (t >> 5) % N;
    int b = t / (N * 32);
    int e = (j & 16) ? idx[2 * b + 1] : idx[2 * b];
    int r = j & 15;
    out[t] = f2bf(Bsrc[((size_t)e * 16 + r) * N + n]);
  }
}

// ---- skinny MFMA GEMM with split-K ----
template <int N2>
__global__ __launch_bounds__(256) void k_skinny(
    const u16* __restrict__ A, const u16* __restrict__ BT,
    float* __restrict__ part, int M, int K, int total_iters, int iters_per_chunk) {
  __shared__ u16 sA[128 * 64];
  __shared__ u16 sB[N2 * 64];
  int nm = M >> 7;
  int bm = blockIdx.x % nm, chunk = blockIdx.x / nm;
  int m0 = bm << 7;
  int batch = m0 >> 11;
  int tid = threadIdx.x, lane = tid & 63, w = tid >> 6;
  int kb = chunk * iters_per_chunk;
  int ke = min(total_iters, kb + iters_per_chunk);

  const u16* Bb = BT + (size_t)batch * N2 * K;

  const u16* ga[4]; u16* la[4];
  #pragma unroll
  for (int t = 0; t < 4; ++t) {
    int cb = 4 * w + t;
    int q = cb * 64 + lane;
    int row = q >> 3;
    int c = (q & 7) ^ (row & 7);
    ga[t] = A + (size_t)(m0 + row) * K + (size_t)kb * 64 + c * 8;
    la[t] = sA + cb * 512;
  }
  constexpr int nB = N2 / 32;
  const u16* gb[nB]; u16* lb[nB];
  #pragma unroll
  for (int t = 0; t < nB; ++t) {
    int cb = nB * w + t;
    int q = cb * 64 + lane;
    int row = q >> 3;
    int c = (q & 7) ^ (row & 7);
    gb[t] = Bb + (size_t)row * K + (size_t)kb * 64 + c * 8;
    lb[t] = sB + cb * 512;
  }

  f32x4 acc[2][N2 / 16] = {};
  for (int kt = kb; kt < ke; ++kt) {
    #pragma unroll
    for (int t = 0; t < 4; ++t) { g2l16(ga[t], la[t]); ga[t] += 64; }
    #pragma unroll
    for (int t = 0; t < nB; ++t) { g2l16(gb[t], lb[t]); gb[t] += 64; }
    __syncthreads();
    #pragma unroll
    for (int ks = 0; ks < 2; ++ks) {
      int cb0 = ks * 4 + (lane >> 4);
      bf16x8 af[2], bfr[N2 / 16];
      #pragma unroll
      for (int mi = 0; mi < 2; ++mi) {
        int row = 32 * w + mi * 16 + (lane & 15);
        af[mi] = *(const bf16x8*)(sA + (row * 8 + (cb0 ^ (row & 7))) * 8);
      }
      #pragma unroll
      for (int ni = 0; ni < N2 / 16; ++ni) {
        int row = ni * 16 + (lane & 15);
        bfr[ni] = *(const bf16x8*)(sB + (row * 8 + (cb0 ^ (row & 7))) * 8);
      }
      #pragma unroll
      for (int mi = 0; mi < 2; ++mi)
        #pragma unroll
        for (int ni = 0; ni < N2 / 16; ++ni)
          acc[mi][ni] = __builtin_amdgcn_mfma_f32_16x16x32_bf16(
              af[mi], bfr[ni], acc[mi][ni], 0, 0, 0);
    }
    __syncthreads();
  }

  int rb = (lane >> 4) * 4, cc = lane & 15;
  #pragma unroll
  for (int mi = 0; mi < 2; ++mi)
    #pragma unroll
    for (int ni = 0; ni < N2 / 16; ++ni)
      #pragma unroll
      for (int reg = 0; reg < 4; ++reg) {
        int gr = m0 + 32 * w + mi * 16 + rb + reg;
        int gc = ni * 16 + cc;
        part[((size_t)chunk * M + gr) * N2 + gc] = acc[mi][ni][reg];
      }
}

// ---- finalize split-K: out = bf16(2 * sum_chunks part) ----
__global__ void k_fin(const float* __restrict__ part, u16* __restrict__ out0,
                      u16* __restrict__ out1, int M, int N2, int nch) {
  int t = blockIdx.x * 256 + threadIdx.x;
  if (t >= M * N2) return;
  float s = 0.f;
  for (int c = 0; c < nch; ++c) s += part[(size_t)c * M * N2 + t];
  int j = t % N2, bs = t / N2;
  u16 v = f2bf(2.0f * s);
  if (N2 == 64) {
    if (j < 32) out0[(size_t)bs * 32 + j] = v;
    else        out1[(size_t)bs * 32 + (j - 32)] = v;
  } else {
    out0[(size_t)bs * 32 + j] = v;
  }
}

// ================= fused gate+up GEMM =================
// One block computes BOTH gate and up 128x128 output tiles for (m0,n0):
// A (xb) staged ONCE per K-tile, Wg-tile and Wu-tile staged alongside;
// 32 MFMA per ks (16 gate + 16 up) against one A-fragment load. Epilogue
// h = silu(g)*u written directly (no gbuf round-trip, one fewer bf16 round).
// LDS 48 KB -> 2 blocks/CU; acc 2x[4][4] f32x4 = 128 VGPR -> launch_bounds
// (256,2) gives the allocator the full 256-VGPR budget (2 waves/SIMD).
__global__ __launch_bounds__(256, 2)
void k_gemmGU(const u16* __restrict__ A, const u16* __restrict__ Bg_,
              const u16* __restrict__ Bu_,
              const u16* __restrict__ A2g, const u16* __restrict__ A2u,
              const u16* __restrict__ B2g, const u16* __restrict__ B2u,
              u16* __restrict__ Out, int N, int K) {
  __shared__ u16 sA[128 * 64];
  __shared__ u16 sG[128 * 64];
  __shared__ u16 sU[128 * 64];
  int nt = N >> 7;
  int nm = gridDim.x / nt;
  int perx = nm >> 3;
  int xcd = blockIdx.x & 7;
  int v = blockIdx.x >> 3;
  int bn = v / perx;
  int bm = xcd * perx + (v - bn * perx);
  int m0 = bm << 7, n0 = bn << 7;
  int tid = threadIdx.x, lane = tid & 63, w = tid >> 6;
  int mo = (w & 1) << 6, no = (w >> 1) << 6;

  const u16* ga[4]; const u16* gg[4]; const u16* gu[4];
  u16* la[4]; u16* lg[4]; u16* lu[4];
  #pragma unroll
  for (int t = 0; t < 4; ++t) {
    int cb = 4 * w + t;
    int q = cb * 64 + lane;
    int row = q >> 3;
    int c = (q & 7) ^ (row & 7);
    ga[t] = A + (size_t)(m0 + row) * K + c * 8;
    gg[t] = Bg_ + (size_t)(n0 + row) * K + c * 8;
    gu[t] = Bu_ + (size_t)(n0 + row) * K + c * 8;
    la[t] = sA + cb * 512;
    lg[t] = sG + cb * 512;
    lu[t] = sU + cb * 512;
  }

  f32x4 accg[4][4] = {};
  f32x4 accu[4][4] = {};

  int kiters = K >> 6;
  for (int kt = 0; kt < kiters; ++kt) {
    #pragma unroll
    for (int t = 0; t < 4; ++t) { g2l16(ga[t], la[t]); ga[t] += 64; }
    #pragma unroll
    for (int t = 0; t < 4; ++t) { g2l16(gg[t], lg[t]); gg[t] += 64; }
    #pragma unroll
    for (int t = 0; t < 4; ++t) { g2l16(gu[t], lu[t]); gu[t] += 64; }
    __syncthreads();
    #pragma unroll
    for (int ks = 0; ks < 2; ++ks) {
      bf16x8 af[4], bgf[4], buf_[4];
      int cb0 = ks * 4 + (lane >> 4);
      #pragma unroll
      for (int mi = 0; mi < 4; ++mi) {
        int row = mo + mi * 16 + (lane & 15);
        af[mi] = *(const bf16x8*)(sA + (row * 8 + (cb0 ^ (row & 7))) * 8);
      }
      #pragma unroll
      for (int ni = 0; ni < 4; ++ni) {
        int row = no + ni * 16 + (lane & 15);
        bgf[ni] = *(const bf16x8*)(sG + (row * 8 + (cb0 ^ (row & 7))) * 8);
        buf_[ni] = *(const bf16x8*)(sU + (row * 8 + (cb0 ^ (row & 7))) * 8);
      }
      #pragma unroll
      for (int mi = 0; mi < 4; ++mi)
        #pragma unroll
        for (int ni = 0; ni < 4; ++ni) {
          accg[mi][ni] = __builtin_amdgcn_mfma_f32_16x16x32_bf16(
              af[mi], bgf[ni], accg[mi][ni], 0, 0, 0);
          accu[mi][ni] = __builtin_amdgcn_mfma_f32_16x16x32_bf16(
              af[mi], buf_[ni], accu[mi][ni], 0, 0, 0);
        }
    }
    __syncthreads();
  }

  // LoRA extra K=32 step: gate uses (A2g,B2g), up uses (A2u,B2u)
  {
    int batch = m0 >> 11;
    const u16* B2gb = B2g + (size_t)batch * N * 32;
    const u16* B2ub = B2u + (size_t)batch * N * 32;
    #pragma unroll
    for (int t = 0; t < 2; ++t) {
      int cb = 2 * w + t;
      int q = cb * 64 + lane;
      int row = q >> 2;
      int c = (q & 3) ^ (row & 3);
      g2l16(A2g + (size_t)(m0 + row) * 32 + c * 8, sA + cb * 512);
      g2l16(A2u + (size_t)(m0 + row) * 32 + c * 8, sA + 4096 + cb * 512);
      g2l16(B2gb + (size_t)(n0 + row) * 32 + c * 8, sG + cb * 512);
      g2l16(B2ub + (size_t)(n0 + row) * 32 + c * 8, sU + cb * 512);
    }
    __syncthreads();
    int c0 = lane >> 4;
    bf16x8 ag2[4], au2[4], bg2[4], bu2[4];
    #pragma unroll
    for (int mi = 0; mi < 4; ++mi) {
      int row = mo + mi * 16 + (lane & 15);
      ag2[mi] = *(const bf16x8*)(sA + (row * 4 + (c0 ^ (row & 3))) * 8);
      au2[mi] = *(const bf16x8*)(sA + 4096 + (row * 4 + (c0 ^ (row & 3))) * 8);
    }
    #pragma unroll
    for (int ni = 0; ni < 4; ++ni) {
      int row = no + ni * 16 + (lane & 15);
      bg2[ni] = *(const bf16x8*)(sG + (row * 4 + (c0 ^ (row & 3))) * 8);
      bu2[ni] = *(const bf16x8*)(sU + (row * 4 + (c0 ^ (row & 3))) * 8);
    }
    #pragma unroll
    for (int mi = 0; mi < 4; ++mi)
      #pragma unroll
      for (int ni = 0; ni < 4; ++ni) {
        accg[mi][ni] = __builtin_amdgcn_mfma_f32_16x16x32_bf16(
            ag2[mi], bg2[ni], accg[mi][ni], 0, 0, 0);
        accu[mi][ni] = __builtin_amdgcn_mfma_f32_16x16x32_bf16(
            au2[mi], bu2[ni], accu[mi][ni], 0, 0, 0);
      }
  }

  // epilogue: h = silu(g) * u, bf16
  int rb = (lane >> 4) * 4;
  int cc = lane & 15;
  #pragma unroll
  for (int mi = 0; mi < 4; ++mi) {
    #pragma unroll
    for (int ni = 0; ni < 4; ++ni) {
      #pragma unroll
      for (int reg = 0; reg < 4; ++reg) {
        int gr = m0 + mo + mi * 16 + rb + reg;
        int gc = n0 + no + ni * 16 + cc;
        size_t pos = (size_t)gr * N + gc;
        float gvv = accg[mi][ni][reg];
        float uvv = accu[mi][ni][reg];
        gvv = gvv / (1.f + __expf(-gvv));
        Out[pos] = f2bf(gvv * uvv);
      }
    }
  }
}

// ---- main GEMM with XCD-aware L2 swizzle (down projection) ----
__global__ __launch_bounds__(256, 3)
void k_gemm(const u16* __restrict__ A, const u16* __restrict__ Bm,
            const u16* __restrict__ A2, const u16* __restrict__ B2,
            const u16* Gprev, void* Out,
            int N, int K, int mode) {
  __shared__ u16 sA[128 * 64];
  __shared__ u16 sB[128 * 64];
  int nt = N >> 7;
  int nm = gridDim.x / nt;
  int perx = nm >> 3;                 // bm strips per XCD
  int xcd = blockIdx.x & 7;
  int v = blockIdx.x >> 3;            // within-XCD linear index
  int bn = v / perx;
  int bm = xcd * perx + (v - bn * perx);
  int m0 = bm << 7, n0 = bn << 7;
  int tid = threadIdx.x, lane = tid & 63, w = tid >> 6;
  int mo = (w & 1) << 6, no = (w >> 1) << 6;

  const u16* ga[4]; const u16* gb[4];
  u16* la[4]; u16* lb[4];
  #pragma unroll
  for (int t = 0; t < 4; ++t) {
    int cb = 4 * w + t;
    int q = cb * 64 + lane;
    int row = q >> 3;
    int c = (q & 7) ^ (row & 7);
    ga[t] = A + (size_t)(m0 + row) * K + c * 8;
    gb[t] = Bm + (size_t)(n0 + row) * K + c * 8;
    la[t] = sA + cb * 512;
    lb[t] = sB + cb * 512;
  }

  f32x4 acc[4][4] = {};

  int kiters = K >> 6;
  for (int kt = 0; kt < kiters; ++kt) {
    #pragma unroll
    for (int t = 0; t < 4; ++t) { g2l16(ga[t], la[t]); ga[t] += 64; }
    #pragma unroll
    for (int t = 0; t < 4; ++t) { g2l16(gb[t], lb[t]); gb[t] += 64; }
    __syncthreads();
    #pragma unroll
    for (int ks = 0; ks < 2; ++ks) {
      bf16x8 af[4], bfr[4];
      int cb0 = ks * 4 + (lane >> 4);
      #pragma unroll
      for (int mi = 0; mi < 4; ++mi) {
        int row = mo + mi * 16 + (lane & 15);
        af[mi] = *(const bf16x8*)(sA + (row * 8 + (cb0 ^ (row & 7))) * 8);
      }
      #pragma unroll
      for (int ni = 0; ni < 4; ++ni) {
        int row = no + ni * 16 + (lane & 15);
        bfr[ni] = *(const bf16x8*)(sB + (row * 8 + (cb0 ^ (row & 7))) * 8);
      }
      #pragma unroll
      for (int mi = 0; mi < 4; ++mi)
        #pragma unroll
        for (int ni = 0; ni < 4; ++ni)
          acc[mi][ni] = __builtin_amdgcn_mfma_f32_16x16x32_bf16(
              af[mi], bfr[ni], acc[mi][ni], 0, 0, 0);
    }
    __syncthreads();
  }

  // LoRA extra K=32 step
  {
    int batch = m0 >> 11;
    const u16* B2b = B2 + (size_t)batch * N * 32;
    #pragma unroll
    for (int t = 0; t < 2; ++t) {
      int cb = 2 * w + t;
      int q = cb * 64 + lane;
      int row = q >> 2;
      int c = (q & 3) ^ (row & 3);
      g2l16(A2 + (size_t)(m0 + row) * 32 + c * 8, sA + cb * 512);
      g2l16(B2b + (size_t)(n0 + row) * 32 + c * 8, sB + cb * 512);
    }
    __syncthreads();
    bf16x8 af[4], bfr[4];
    int c0 = lane >> 4;
    #pragma unroll
    for (int mi = 0; mi < 4; ++mi) {
      int row = mo + mi * 16 + (lane & 15);
      af[mi] = *(const bf16x8*)(sA + (row * 4 + (c0 ^ (row & 3))) * 8);
    }
    #pragma unroll
    for (int ni = 0; ni < 4; ++ni) {
      int row = no + ni * 16 + (lane & 15);
      bfr[ni] = *(const bf16x8*)(sB + (row * 4 + (c0 ^ (row & 3))) * 8);
    }
    #pragma unroll
    for (int mi = 0; mi < 4; ++mi)
      #pragma unroll
      for (int ni = 0; ni < 4; ++ni)
        acc[mi][ni] = __builtin_amdgcn_mfma_f32_16x16x32_bf16(
            af[mi], bfr[ni], acc[mi][ni], 0, 0, 0);
  }

  int rb = (lane >> 4) * 4;
  int cc = lane & 15;
  #pragma unroll
  for (int mi = 0; mi < 4; ++mi) {
    #pragma unroll
    for (int ni = 0; ni < 4; ++ni) {
      #pragma unroll
      for (int reg = 0; reg < 4; ++reg) {
        int gr = m0 + mo + mi * 16 + rb + reg;
        int gc = n0 + no + ni * 16 + cc;
        size_t pos = (size_t)gr * N + gc;
        float vv = acc[mi][ni][reg];
        if (mode == 0) {
          vv = vv / (1.f + __expf(-vv));
          ((u16*)Out)[pos] = f2bf(vv);
        } else if (mode == 1) {
          float gg = bf2f(Gprev[pos]);
          ((u16*)Out)[pos] = f2bf(gg * vv);
        } else {
          ((float*)Out)[pos] = vv;
        }
      }
    }
  }
}

extern "C" void kernel_launch(void* const* d_in, const int* in_sizes, int n_in,
                              void* d_out, int out_size, void* d_ws, size_t ws_size,
                              hipStream_t stream) {
  const float* x  = (const float*)d_in[0];
  const float* gv = (const float*)d_in[1];
  const float* Wg = (const float*)d_in[2];
  const float* Ag = (const float*)d_in[3];
  const float* Bg = (const float*)d_in[4];
  const float* Wu = (const float*)d_in[5];
  const float* Au = (const float*)d_in[6];
  const float* Bu = (const float*)d_in[7];
  const float* Wd = (const float*)d_in[8];
  const float* Ad = (const float*)d_in[9];
  const float* Bd = (const float*)d_in[10];
  float* out = (float*)d_out;

  char* ws = (char*)d_ws;
  size_t off = 0;
  auto alloc = [&](size_t bytes) -> void* {
    void* p = ws + off;
    off = (off + bytes + 255) & ~(size_t)255;
    return p;
  };
  int* idx  = (int*)alloc(32);
  u16* xb   = (u16*)alloc((size_t)8192 * 2048 * 2);
  u16* Wgb  = (u16*)alloc((size_t)5504 * 2048 * 2);
  u16* Wub  = (u16*)alloc((size_t)5504 * 2048 * 2);
  u16* Wdb  = (u16*)alloc((size_t)2048 * 5504 * 2);
  u16* xag  = (u16*)alloc((size_t)8192 * 32 * 2);
  u16* xau  = (u16*)alloc((size_t)8192 * 32 * 2);
  u16* ha   = (u16*)alloc((size_t)8192 * 32 * 2);
  u16* BgT  = (u16*)alloc((size_t)4 * 5504 * 32 * 2);
  u16* BuT  = (u16*)alloc((size_t)4 * 5504 * 32 * 2);
  u16* BdT  = (u16*)alloc((size_t)4 * 2048 * 32 * 2);
  u16* AxT  = (u16*)alloc((size_t)4 * 64 * 2048 * 2);
  u16* AdT  = (u16*)alloc((size_t)4 * 32 * 5504 * 2);
  u16* gbuf = (u16*)alloc((size_t)8192 * 5504 * 2);
  if (off > ws_size) return;

  float* part_xa = (float*)gbuf;   // dead region until fused GEMM
  float* part_ha = (float*)Wgb;    // dead region after fused GEMM

  k_top2<<<1, 64, 0, stream>>>(gv, idx);
  k_cast<<<16384, 256, 0, stream>>>(x, xb, 4194304);
  k_cast<<<11008, 256, 0, stream>>>(Wg, Wgb, 2818048);
  k_cast<<<11008, 256, 0, stream>>>(Wu, Wub, 2818048);
  k_cast<<<11008, 256, 0, stream>>>(Wd, Wdb, 2818048);
  k_aT<<<2048, 256, 0, stream>>>(Ag, Au, idx, AxT, 2048, 64);
  k_aT<<<2752, 256, 0, stream>>>(Ad, Ad, idx, AdT, 5504, 32);
  k_bT<<<2752, 256, 0, stream>>>(Bg, idx, BgT, 5504);
  k_bT<<<2752, 256, 0, stream>>>(Bu, idx, BuT, 5504);
  k_bT<<<1024, 256, 0, stream>>>(Bd, idx, BdT, 2048);

  // xa: [8192 x 64] = xb @ AxT^T, split-K 4 chunks (K=2048)
  k_skinny<64><<<64 * 4, 256, 0, stream>>>(xb, AxT, part_xa, 8192, 2048, 32, 8);
  k_fin<<<2048, 256, 0, stream>>>(part_xa, xag, xau, 8192, 64, 4);

  // fused gate+up: h = silu(x@Wg^T + lora_g) * (x@Wu^T + lora_u) -> gbuf
  k_gemmGU<<<64 * 43, 256, 0, stream>>>(xb, Wgb, Wub, xag, xau, BgT, BuT,
                                        gbuf, 5504, 2048);

  // ha: [8192 x 32] = h @ AdT^T, split-K 4 chunks (K=5504)
  k_skinny<32><<<64 * 4, 256, 0, stream>>>(gbuf, AdT, part_ha, 8192, 5504, 86, 22);
  k_fin<<<1024, 256, 0, stream>>>(part_ha, ha, ha, 8192, 32, 4);

  // down: out = h@Wd^T + lora (fp32)
  k_gemm<<<64 * 16, 256, 0, stream>>>(gbuf, Wdb, ha, BdT, (const u16*)nullptr,
                                      out, 2048, 5504, 2);
}

// Round 4
// 806.686 us; speedup vs baseline: 1.1313x; 1.0147x over previous
//
#include <hip/hip_runtime.h>
#include <stdint.h>

typedef unsigned short u16;
typedef __bf16 bf16x8 __attribute__((ext_vector_type(8)));
typedef float f32x4 __attribute__((ext_vector_type(4)));

#define AS1 __attribute__((address_space(1)))
#define AS3 __attribute__((address_space(3)))

__device__ __forceinline__ void g2l16(const void* g, void* l) {
  __builtin_amdgcn_global_load_lds((AS1 void*)(void*)g, (AS3 void*)l, 16, 0, 0);
}

__device__ __forceinline__ u16 f2bf(float f) {
  union { float f; uint32_t u; } v; v.f = f;
  return (u16)((v.u + 0x7fffu + ((v.u >> 16) & 1u)) >> 16);
}
__device__ __forceinline__ float bf2f(u16 b) {
  union { uint32_t u; float f; } v; v.u = ((uint32_t)b) << 16;
  return v.f;
}

// ---- merged fp32 -> bf16 casts: x, Wg, Wu, Wd in one launch ----
__global__ void k_cast4(const float* __restrict__ x, u16* __restrict__ xb,
                        const float* __restrict__ Wg, u16* __restrict__ Wgb,
                        const float* __restrict__ Wu, u16* __restrict__ Wub,
                        const float* __restrict__ Wd, u16* __restrict__ Wdb) {
  int i = blockIdx.x * 256 + threadIdx.x;
  const float* in; u16* out; int j;
  if (i < 4194304) { in = x; out = xb; j = i; }
  else if (i < 4194304 + 2818048) { in = Wg; out = Wgb; j = i - 4194304; }
  else if (i < 4194304 + 2 * 2818048) { in = Wu; out = Wub; j = i - 4194304 - 2818048; }
  else { in = Wd; out = Wdb; j = i - 4194304 - 2 * 2818048; }
  float4 v = ((const float4*)in)[j];
  ushort4 o = make_ushort4(f2bf(v.x), f2bf(v.y), f2bf(v.z), f2bf(v.w));
  ((ushort4*)out)[j] = o;
}

// ---- merged LoRA prep: top-2 (per-block recompute) + A^T panels + B_cat^T ----
// regions (thread-linear): AxT 524288 | AdT 704512 | BgT 704512 | BuT 704512
// | BdT 262144; total 2899968 = 11328 * 256
__global__ void k_prep(const float* __restrict__ gv,
                       const float* __restrict__ Ag, const float* __restrict__ Au,
                       const float* __restrict__ Ad,
                       const float* __restrict__ Bg, const float* __restrict__ Bu,
                       const float* __restrict__ Bd,
                       u16* __restrict__ AxT, u16* __restrict__ AdT,
                       u16* __restrict__ BgT, u16* __restrict__ BuT,
                       u16* __restrict__ BdT) {
  __shared__ int sidx[8];
  if (threadIdx.x == 0) {
    #pragma unroll
    for (int b = 0; b < 4; ++b) {
      const float* g = gv + b * 8;
      int i1 = 0; float v1 = g[0];
      for (int e = 1; e < 8; ++e) if (g[e] > v1) { v1 = g[e]; i1 = e; }
      int i2 = -1; float v2 = -3.0e38f;
      for (int e = 0; e < 8; ++e) if (e != i1 && g[e] > v2) { v2 = g[e]; i2 = e; }
      sidx[2 * b] = i1; sidx[2 * b + 1] = i2;
    }
  }
  __syncthreads();
  int t = blockIdx.x * 256 + threadIdx.x;
  if (t < 524288) {  // AxT: Kd=2048, jmax=64 (gate|up stacked)
    int h = t % 2048;
    int j = (t / 2048) & 63;
    int b = t / (2048 * 64);
    const float* src = (j >= 32) ? Au : Ag;
    int jj = j & 31;
    int e = sidx[2 * b + ((jj >> 4) & 1)];
    AxT[t] = f2bf(src[((size_t)e * 2048 + h) * 16 + (jj & 15)]);
    return;
  }
  t -= 524288;
  if (t < 704512) {  // AdT: Kd=5504, jmax=32
    int h = t % 5504;
    int j = (t / 5504) & 31;
    int b = t / (5504 * 32);
    int e = sidx[2 * b + ((j >> 4) & 1)];
    AdT[t] = f2bf(Ad[((size_t)e * 5504 + h) * 16 + (j & 15)]);
    return;
  }
  t -= 704512;
  if (t < 704512) {  // BgT: N=5504
    int j = t & 31;
    int n = (t >> 5) % 5504;
    int b = t / (5504 * 32);
    int e = (j & 16) ? sidx[2 * b + 1] : sidx[2 * b];
    BgT[t] = f2bf(Bg[((size_t)e * 16 + (j & 15)) * 5504 + n]);
    return;
  }
  t -= 704512;
  if (t < 704512) {  // BuT: N=5504
    int j = t & 31;
    int n = (t >> 5) % 5504;
    int b = t / (5504 * 32);
    int e = (j & 16) ? sidx[2 * b + 1] : sidx[2 * b];
    BuT[t] = f2bf(Bu[((size_t)e * 16 + (j & 15)) * 5504 + n]);
    return;
  }
  t -= 704512;
  if (t < 262144) {  // BdT: N=2048
    int j = t & 31;
    int n = (t >> 5) % 2048;
    int b = t / (2048 * 32);
    int e = (j & 16) ? sidx[2 * b + 1] : sidx[2 * b];
    BdT[t] = f2bf(Bd[((size_t)e * 16 + (j & 15)) * 2048 + n]);
  }
}

// ---- skinny MFMA GEMM with split-K ----
template <int N2>
__global__ __launch_bounds__(256) void k_skinny(
    const u16* __restrict__ A, const u16* __restrict__ BT,
    float* __restrict__ part, int M, int K, int total_iters, int iters_per_chunk) {
  __shared__ u16 sA[128 * 64];
  __shared__ u16 sB[N2 * 64];
  int nm = M >> 7;
  int bm = blockIdx.x % nm, chunk = blockIdx.x / nm;
  int m0 = bm << 7;
  int batch = m0 >> 11;
  int tid = threadIdx.x, lane = tid & 63, w = tid >> 6;
  int kb = chunk * iters_per_chunk;
  int ke = min(total_iters, kb + iters_per_chunk);

  const u16* Bb = BT + (size_t)batch * N2 * K;

  const u16* ga[4]; u16* la[4];
  #pragma unroll
  for (int t = 0; t < 4; ++t) {
    int cb = 4 * w + t;
    int q = cb * 64 + lane;
    int row = q >> 3;
    int c = (q & 7) ^ (row & 7);
    ga[t] = A + (size_t)(m0 + row) * K + (size_t)kb * 64 + c * 8;
    la[t] = sA + cb * 512;
  }
  constexpr int nB = N2 / 32;
  const u16* gb[nB]; u16* lb[nB];
  #pragma unroll
  for (int t = 0; t < nB; ++t) {
    int cb = nB * w + t;
    int q = cb * 64 + lane;
    int row = q >> 3;
    int c = (q & 7) ^ (row & 7);
    gb[t] = Bb + (size_t)row * K + (size_t)kb * 64 + c * 8;
    lb[t] = sB + cb * 512;
  }

  f32x4 acc[2][N2 / 16] = {};
  for (int kt = kb; kt < ke; ++kt) {
    #pragma unroll
    for (int t = 0; t < 4; ++t) { g2l16(ga[t], la[t]); ga[t] += 64; }
    #pragma unroll
    for (int t = 0; t < nB; ++t) { g2l16(gb[t], lb[t]); gb[t] += 64; }
    __syncthreads();
    #pragma unroll
    for (int ks = 0; ks < 2; ++ks) {
      int cb0 = ks * 4 + (lane >> 4);
      bf16x8 af[2], bfr[N2 / 16];
      #pragma unroll
      for (int mi = 0; mi < 2; ++mi) {
        int row = 32 * w + mi * 16 + (lane & 15);
        af[mi] = *(const bf16x8*)(sA + (row * 8 + (cb0 ^ (row & 7))) * 8);
      }
      #pragma unroll
      for (int ni = 0; ni < N2 / 16; ++ni) {
        int row = ni * 16 + (lane & 15);
        bfr[ni] = *(const bf16x8*)(sB + (row * 8 + (cb0 ^ (row & 7))) * 8);
      }
      #pragma unroll
      for (int mi = 0; mi < 2; ++mi)
        #pragma unroll
        for (int ni = 0; ni < N2 / 16; ++ni)
          acc[mi][ni] = __builtin_amdgcn_mfma_f32_16x16x32_bf16(
              af[mi], bfr[ni], acc[mi][ni], 0, 0, 0);
    }
    __syncthreads();
  }

  int rb = (lane >> 4) * 4, cc = lane & 15;
  #pragma unroll
  for (int mi = 0; mi < 2; ++mi)
    #pragma unroll
    for (int ni = 0; ni < N2 / 16; ++ni)
      #pragma unroll
      for (int reg = 0; reg < 4; ++reg) {
        int gr = m0 + 32 * w + mi * 16 + rb + reg;
        int gc = ni * 16 + cc;
        part[((size_t)chunk * M + gr) * N2 + gc] = acc[mi][ni][reg];
      }
}

// ---- finalize split-K: out = bf16(2 * sum_chunks part) ----
__global__ void k_fin(const float* __restrict__ part, u16* __restrict__ out0,
                      u16* __restrict__ out1, int M, int N2, int nch) {
  int t = blockIdx.x * 256 + threadIdx.x;
  if (t >= M * N2) return;
  float s = 0.f;
  for (int c = 0; c < nch; ++c) s += part[(size_t)c * M * N2 + t];
  int j = t % N2, bs = t / N2;
  u16 v = f2bf(2.0f * s);
  if (N2 == 64) {
    if (j < 32) out0[(size_t)bs * 32 + j] = v;
    else        out1[(size_t)bs * 32 + (j - 32)] = v;
  } else {
    out0[(size_t)bs * 32 + j] = v;
  }
}

// ================= fused gate+up GEMM =================
// One block computes BOTH gate and up 128x128 output tiles for (m0,n0):
// A (xb) staged ONCE per K-tile, Wg-tile and Wu-tile staged alongside;
// 32 MFMA per ks (16 gate + 16 up) against one A-fragment load. Epilogue
// h = silu(g)*u written directly (no gbuf round-trip, one fewer bf16 round).
__global__ __launch_bounds__(256, 2)
void k_gemmGU(const u16* __restrict__ A, const u16* __restrict__ Bg_,
              const u16* __restrict__ Bu_,
              const u16* __restrict__ A2g, const u16* __restrict__ A2u,
              const u16* __restrict__ B2g, const u16* __restrict__ B2u,
              u16* __restrict__ Out, int N, int K) {
  __shared__ u16 sA[128 * 64];
  __shared__ u16 sG[128 * 64];
  __shared__ u16 sU[128 * 64];
  int nt = N >> 7;
  int nm = gridDim.x / nt;
  int perx = nm >> 3;
  int xcd = blockIdx.x & 7;
  int v = blockIdx.x >> 3;
  int bn = v / perx;
  int bm = xcd * perx + (v - bn * perx);
  int m0 = bm << 7, n0 = bn << 7;
  int tid = threadIdx.x, lane = tid & 63, w = tid >> 6;
  int mo = (w & 1) << 6, no = (w >> 1) << 6;

  const u16* ga[4]; const u16* gg[4]; const u16* gu[4];
  u16* la[4]; u16* lg[4]; u16* lu[4];
  #pragma unroll
  for (int t = 0; t < 4; ++t) {
    int cb = 4 * w + t;
    int q = cb * 64 + lane;
    int row = q >> 3;
    int c = (q & 7) ^ (row & 7);
    ga[t] = A + (size_t)(m0 + row) * K + c * 8;
    gg[t] = Bg_ + (size_t)(n0 + row) * K + c * 8;
    gu[t] = Bu_ + (size_t)(n0 + row) * K + c * 8;
    la[t] = sA + cb * 512;
    lg[t] = sG + cb * 512;
    lu[t] = sU + cb * 512;
  }

  f32x4 accg[4][4] = {};
  f32x4 accu[4][4] = {};

  int kiters = K >> 6;
  for (int kt = 0; kt < kiters; ++kt) {
    #pragma unroll
    for (int t = 0; t < 4; ++t) { g2l16(ga[t], la[t]); ga[t] += 64; }
    #pragma unroll
    for (int t = 0; t < 4; ++t) { g2l16(gg[t], lg[t]); gg[t] += 64; }
    #pragma unroll
    for (int t = 0; t < 4; ++t) { g2l16(gu[t], lu[t]); gu[t] += 64; }
    __syncthreads();
    #pragma unroll
    for (int ks = 0; ks < 2; ++ks) {
      bf16x8 af[4], bgf[4], buf_[4];
      int cb0 = ks * 4 + (lane >> 4);
      #pragma unroll
      for (int mi = 0; mi < 4; ++mi) {
        int row = mo + mi * 16 + (lane & 15);
        af[mi] = *(const bf16x8*)(sA + (row * 8 + (cb0 ^ (row & 7))) * 8);
      }
      #pragma unroll
      for (int ni = 0; ni < 4; ++ni) {
        int row = no + ni * 16 + (lane & 15);
        bgf[ni] = *(const bf16x8*)(sG + (row * 8 + (cb0 ^ (row & 7))) * 8);
        buf_[ni] = *(const bf16x8*)(sU + (row * 8 + (cb0 ^ (row & 7))) * 8);
      }
      #pragma unroll
      for (int mi = 0; mi < 4; ++mi)
        #pragma unroll
        for (int ni = 0; ni < 4; ++ni) {
          accg[mi][ni] = __builtin_amdgcn_mfma_f32_16x16x32_bf16(
              af[mi], bgf[ni], accg[mi][ni], 0, 0, 0);
          accu[mi][ni] = __builtin_amdgcn_mfma_f32_16x16x32_bf16(
              af[mi], buf_[ni], accu[mi][ni], 0, 0, 0);
        }
    }
    __syncthreads();
  }

  // LoRA extra K=32 step: gate uses (A2g,B2g), up uses (A2u,B2u)
  {
    int batch = m0 >> 11;
    const u16* B2gb = B2g + (size_t)batch * N * 32;
    const u16* B2ub = B2u + (size_t)batch * N * 32;
    #pragma unroll
    for (int t = 0; t < 2; ++t) {
      int cb = 2 * w + t;
      int q = cb * 64 + lane;
      int row = q >> 2;
      int c = (q & 3) ^ (row & 3);
      g2l16(A2g + (size_t)(m0 + row) * 32 + c * 8, sA + cb * 512);
      g2l16(A2u + (size_t)(m0 + row) * 32 + c * 8, sA + 4096 + cb * 512);
      g2l16(B2gb + (size_t)(n0 + row) * 32 + c * 8, sG + cb * 512);
      g2l16(B2ub + (size_t)(n0 + row) * 32 + c * 8, sU + cb * 512);
    }
    __syncthreads();
    int c0 = lane >> 4;
    bf16x8 ag2[4], au2[4], bg2[4], bu2[4];
    #pragma unroll
    for (int mi = 0; mi < 4; ++mi) {
      int row = mo + mi * 16 + (lane & 15);
      ag2[mi] = *(const bf16x8*)(sA + (row * 4 + (c0 ^ (row & 3))) * 8);
      au2[mi] = *(const bf16x8*)(sA + 4096 + (row * 4 + (c0 ^ (row & 3))) * 8);
    }
    #pragma unroll
    for (int ni = 0; ni < 4; ++ni) {
      int row = no + ni * 16 + (lane & 15);
      bg2[ni] = *(const bf16x8*)(sG + (row * 4 + (c0 ^ (row & 3))) * 8);
      bu2[ni] = *(const bf16x8*)(sU + (row * 4 + (c0 ^ (row & 3))) * 8);
    }
    #pragma unroll
    for (int mi = 0; mi < 4; ++mi)
      #pragma unroll
      for (int ni = 0; ni < 4; ++ni) {
        accg[mi][ni] = __builtin_amdgcn_mfma_f32_16x16x32_bf16(
            ag2[mi], bg2[ni], accg[mi][ni], 0, 0, 0);
        accu[mi][ni] = __builtin_amdgcn_mfma_f32_16x16x32_bf16(
            au2[mi], bu2[ni], accu[mi][ni], 0, 0, 0);
      }
  }

  // epilogue: h = silu(g) * u, bf16
  int rb = (lane >> 4) * 4;
  int cc = lane & 15;
  #pragma unroll
  for (int mi = 0; mi < 4; ++mi) {
    #pragma unroll
    for (int ni = 0; ni < 4; ++ni) {
      #pragma unroll
      for (int reg = 0; reg < 4; ++reg) {
        int gr = m0 + mo + mi * 16 + rb + reg;
        int gc = n0 + no + ni * 16 + cc;
        size_t pos = (size_t)gr * N + gc;
        float gvv = accg[mi][ni][reg];
        float uvv = accu[mi][ni][reg];
        gvv = gvv / (1.f + __expf(-gvv));
        Out[pos] = f2bf(gvv * uvv);
      }
    }
  }
}

// ---- main GEMM with XCD-aware L2 swizzle (down projection) ----
__global__ __launch_bounds__(256, 3)
void k_gemm(const u16* __restrict__ A, const u16* __restrict__ Bm,
            const u16* __restrict__ A2, const u16* __restrict__ B2,
            const u16* Gprev, void* Out,
            int N, int K, int mode) {
  __shared__ u16 sA[128 * 64];
  __shared__ u16 sB[128 * 64];
  int nt = N >> 7;
  int nm = gridDim.x / nt;
  int perx = nm >> 3;                 // bm strips per XCD
  int xcd = blockIdx.x & 7;
  int v = blockIdx.x >> 3;            // within-XCD linear index
  int bn = v / perx;
  int bm = xcd * perx + (v - bn * perx);
  int m0 = bm << 7, n0 = bn << 7;
  int tid = threadIdx.x, lane = tid & 63, w = tid >> 6;
  int mo = (w & 1) << 6, no = (w >> 1) << 6;

  const u16* ga[4]; const u16* gb[4];
  u16* la[4]; u16* lb[4];
  #pragma unroll
  for (int t = 0; t < 4; ++t) {
    int cb = 4 * w + t;
    int q = cb * 64 + lane;
    int row = q >> 3;
    int c = (q & 7) ^ (row & 7);
    ga[t] = A + (size_t)(m0 + row) * K + c * 8;
    gb[t] = Bm + (size_t)(n0 + row) * K + c * 8;
    la[t] = sA + cb * 512;
    lb[t] = sB + cb * 512;
  }

  f32x4 acc[4][4] = {};

  int kiters = K >> 6;
  for (int kt = 0; kt < kiters; ++kt) {
    #pragma unroll
    for (int t = 0; t < 4; ++t) { g2l16(ga[t], la[t]); ga[t] += 64; }
    #pragma unroll
    for (int t = 0; t < 4; ++t) { g2l16(gb[t], lb[t]); gb[t] += 64; }
    __syncthreads();
    #pragma unroll
    for (int ks = 0; ks < 2; ++ks) {
      bf16x8 af[4], bfr[4];
      int cb0 = ks * 4 + (lane >> 4);
      #pragma unroll
      for (int mi = 0; mi < 4; ++mi) {
        int row = mo + mi * 16 + (lane & 15);
        af[mi] = *(const bf16x8*)(sA + (row * 8 + (cb0 ^ (row & 7))) * 8);
      }
      #pragma unroll
      for (int ni = 0; ni < 4; ++ni) {
        int row = no + ni * 16 + (lane & 15);
        bfr[ni] = *(const bf16x8*)(sB + (row * 8 + (cb0 ^ (row & 7))) * 8);
      }
      #pragma unroll
      for (int mi = 0; mi < 4; ++mi)
        #pragma unroll
        for (int ni = 0; ni < 4; ++ni)
          acc[mi][ni] = __builtin_amdgcn_mfma_f32_16x16x32_bf16(
              af[mi], bfr[ni], acc[mi][ni], 0, 0, 0);
    }
    __syncthreads();
  }

  // LoRA extra K=32 step
  {
    int batch = m0 >> 11;
    const u16* B2b = B2 + (size_t)batch * N * 32;
    #pragma unroll
    for (int t = 0; t < 2; ++t) {
      int cb = 2 * w + t;
      int q = cb * 64 + lane;
      int row = q >> 2;
      int c = (q & 3) ^ (row & 3);
      g2l16(A2 + (size_t)(m0 + row) * 32 + c * 8, sA + cb * 512);
      g2l16(B2b + (size_t)(n0 + row) * 32 + c * 8, sB + cb * 512);
    }
    __syncthreads();
    bf16x8 af[4], bfr[4];
    int c0 = lane >> 4;
    #pragma unroll
    for (int mi = 0; mi < 4; ++mi) {
      int row = mo + mi * 16 + (lane & 15);
      af[mi] = *(const bf16x8*)(sA + (row * 4 + (c0 ^ (row & 3))) * 8);
    }
    #pragma unroll
    for (int ni = 0; ni < 4; ++ni) {
      int row = no + ni * 16 + (lane & 15);
      bfr[ni] = *(const bf16x8*)(sB + (row * 4 + (c0 ^ (row & 3))) * 8);
    }
    #pragma unroll
    for (int mi = 0; mi < 4; ++mi)
      #pragma unroll
      for (int ni = 0; ni < 4; ++ni)
        acc[mi][ni] = __builtin_amdgcn_mfma_f32_16x16x32_bf16(
            af[mi], bfr[ni], acc[mi][ni], 0, 0, 0);
  }

  int rb = (lane >> 4) * 4;
  int cc = lane & 15;
  #pragma unroll
  for (int mi = 0; mi < 4; ++mi) {
    #pragma unroll
    for (int ni = 0; ni < 4; ++ni) {
      #pragma unroll
      for (int reg = 0; reg < 4; ++reg) {
        int gr = m0 + mo + mi * 16 + rb + reg;
        int gc = n0 + no + ni * 16 + cc;
        size_t pos = (size_t)gr * N + gc;
        float vv = acc[mi][ni][reg];
        if (mode == 0) {
          vv = vv / (1.f + __expf(-vv));
          ((u16*)Out)[pos] = f2bf(vv);
        } else if (mode == 1) {
          float gg = bf2f(Gprev[pos]);
          ((u16*)Out)[pos] = f2bf(gg * vv);
        } else {
          ((float*)Out)[pos] = vv;
        }
      }
    }
  }
}

extern "C" void kernel_launch(void* const* d_in, const int* in_sizes, int n_in,
                              void* d_out, int out_size, void* d_ws, size_t ws_size,
                              hipStream_t stream) {
  const float* x  = (const float*)d_in[0];
  const float* gv = (const float*)d_in[1];
  const float* Wg = (const float*)d_in[2];
  const float* Ag = (const float*)d_in[3];
  const float* Bg = (const float*)d_in[4];
  const float* Wu = (const float*)d_in[5];
  const float* Au = (const float*)d_in[6];
  const float* Bu = (const float*)d_in[7];
  const float* Wd = (const float*)d_in[8];
  const float* Ad = (const float*)d_in[9];
  const float* Bd = (const float*)d_in[10];
  float* out = (float*)d_out;

  char* ws = (char*)d_ws;
  size_t off = 0;
  auto alloc = [&](size_t bytes) -> void* {
    void* p = ws + off;
    off = (off + bytes + 255) & ~(size_t)255;
    return p;
  };
  u16* xb   = (u16*)alloc((size_t)8192 * 2048 * 2);
  u16* Wgb  = (u16*)alloc((size_t)5504 * 2048 * 2);
  u16* Wub  = (u16*)alloc((size_t)5504 * 2048 * 2);
  u16* Wdb  = (u16*)alloc((size_t)2048 * 5504 * 2);
  u16* xag  = (u16*)alloc((size_t)8192 * 32 * 2);
  u16* xau  = (u16*)alloc((size_t)8192 * 32 * 2);
  u16* ha   = (u16*)alloc((size_t)8192 * 32 * 2);
  u16* BgT  = (u16*)alloc((size_t)4 * 5504 * 32 * 2);
  u16* BuT  = (u16*)alloc((size_t)4 * 5504 * 32 * 2);
  u16* BdT  = (u16*)alloc((size_t)4 * 2048 * 32 * 2);
  u16* AxT  = (u16*)alloc((size_t)4 * 64 * 2048 * 2);
  u16* AdT  = (u16*)alloc((size_t)4 * 32 * 5504 * 2);
  u16* gbuf = (u16*)alloc((size_t)8192 * 5504 * 2);
  if (off > ws_size) return;

  // split-K=16 partial buffers live in dead regions:
  float* part_xa = (float*)gbuf;   // 16*8192*64*4 = 33.5MB <= 90MB, dead until GU
  float* part_ha = (float*)Wgb;    // 16*8192*32*4 = 16.8MB <= 22.5MB, dead after GU

  // merged casts: x, Wg, Wu, Wd (12648448 float4s = 49408 * 256)
  k_cast4<<<49408, 256, 0, stream>>>(x, xb, Wg, Wgb, Wu, Wub, Wd, Wdb);
  // merged LoRA prep (top2 recomputed per block): AxT, AdT, BgT, BuT, BdT
  k_prep<<<11328, 256, 0, stream>>>(gv, Ag, Au, Ad, Bg, Bu, Bd,
                                    AxT, AdT, BgT, BuT, BdT);

  // xa: [8192 x 64] = xb @ AxT^T, split-K 16 chunks (K=2048) -> 4 blocks/CU
  k_skinny<64><<<64 * 16, 256, 0, stream>>>(xb, AxT, part_xa, 8192, 2048, 32, 2);
  k_fin<<<2048, 256, 0, stream>>>(part_xa, xag, xau, 8192, 64, 16);

  // fused gate+up: h = silu(x@Wg^T + lora_g) * (x@Wu^T + lora_u) -> gbuf
  k_gemmGU<<<64 * 43, 256, 0, stream>>>(xb, Wgb, Wub, xag, xau, BgT, BuT,
                                        gbuf, 5504, 2048);

  // ha: [8192 x 32] = h @ AdT^T, split-K 16 chunks (K=5504) -> 4 blocks/CU
  k_skinny<32><<<64 * 16, 256, 0, stream>>>(gbuf, AdT, part_ha, 8192, 5504, 86, 6);
  k_fin<<<1024, 256, 0, stream>>>(part_ha, ha, ha, 8192, 32, 16);

  // down: out = h@Wd^T + lora (fp32)
  k_gemm<<<64 * 16, 256, 0, stream>>>(gbuf, Wdb, ha, BdT, (const u16*)nullptr,
                                      out, 2048, 5504, 2);
}

// Round 5
// 785.771 us; speedup vs baseline: 1.1614x; 1.0266x over previous
//
#include <hip/hip_runtime.h>
#include <stdint.h>

typedef unsigned short u16;
typedef __bf16 bf16x8 __attribute__((ext_vector_type(8)));
typedef float f32x4 __attribute__((ext_vector_type(4)));

#define AS1 __attribute__((address_space(1)))
#define AS3 __attribute__((address_space(3)))

__device__ __forceinline__ void g2l16(const void* g, void* l) {
  __builtin_amdgcn_global_load_lds((AS1 void*)(void*)g, (AS3 void*)l, 16, 0, 0);
}

__device__ __forceinline__ u16 f2bf(float f) {
  union { float f; uint32_t u; } v; v.f = f;
  return (u16)((v.u + 0x7fffu + ((v.u >> 16) & 1u)) >> 16);
}
__device__ __forceinline__ float bf2f(u16 b) {
  union { uint32_t u; float f; } v; v.u = ((uint32_t)b) << 16;
  return v.f;
}

// ---- merged prologue: fp32->bf16 casts (x,Wg,Wu,Wd) + top2 + LoRA panels ----
// blocks [0, 49408): cast region, 12648448 float4s
// blocks [49408, 60736): prep region, 2899968 threads:
//   AxT 524288 | AdT 704512 | BgT 704512 | BuT 704512 | BdT 262144
__global__ void k_pre(const float* __restrict__ x, u16* __restrict__ xb,
                      const float* __restrict__ Wg, u16* __restrict__ Wgb,
                      const float* __restrict__ Wu, u16* __restrict__ Wub,
                      const float* __restrict__ Wd, u16* __restrict__ Wdb,
                      const float* __restrict__ gv,
                      const float* __restrict__ Ag, const float* __restrict__ Au,
                      const float* __restrict__ Ad,
                      const float* __restrict__ Bg, const float* __restrict__ Bu,
                      const float* __restrict__ Bd,
                      u16* __restrict__ AxT, u16* __restrict__ AdT,
                      u16* __restrict__ BgT, u16* __restrict__ BuT,
                      u16* __restrict__ BdT) {
  __shared__ int sidx[8];
  if (blockIdx.x < 49408) {
    int i = blockIdx.x * 256 + threadIdx.x;
    const float* in; u16* out; int j;
    if (i < 4194304) { in = x; out = xb; j = i; }
    else if (i < 4194304 + 2818048) { in = Wg; out = Wgb; j = i - 4194304; }
    else if (i < 4194304 + 2 * 2818048) { in = Wu; out = Wub; j = i - 4194304 - 2818048; }
    else { in = Wd; out = Wdb; j = i - 4194304 - 2 * 2818048; }
    float4 v = ((const float4*)in)[j];
    ushort4 o = make_ushort4(f2bf(v.x), f2bf(v.y), f2bf(v.z), f2bf(v.w));
    ((ushort4*)out)[j] = o;
    return;
  }
  if (threadIdx.x == 0) {
    #pragma unroll
    for (int b = 0; b < 4; ++b) {
      const float* g = gv + b * 8;
      int i1 = 0; float v1 = g[0];
      for (int e = 1; e < 8; ++e) if (g[e] > v1) { v1 = g[e]; i1 = e; }
      int i2 = -1; float v2 = -3.0e38f;
      for (int e = 0; e < 8; ++e) if (e != i1 && g[e] > v2) { v2 = g[e]; i2 = e; }
      sidx[2 * b] = i1; sidx[2 * b + 1] = i2;
    }
  }
  __syncthreads();
  int t = (blockIdx.x - 49408) * 256 + threadIdx.x;
  if (t < 524288) {  // AxT: Kd=2048, jmax=64 (gate|up stacked)
    int h = t % 2048;
    int j = (t / 2048) & 63;
    int b = t / (2048 * 64);
    const float* src = (j >= 32) ? Au : Ag;
    int jj = j & 31;
    int e = sidx[2 * b + ((jj >> 4) & 1)];
    AxT[t] = f2bf(src[((size_t)e * 2048 + h) * 16 + (jj & 15)]);
    return;
  }
  t -= 524288;
  if (t < 704512) {  // AdT: Kd=5504, jmax=32
    int h = t % 5504;
    int j = (t / 5504) & 31;
    int b = t / (5504 * 32);
    int e = sidx[2 * b + ((j >> 4) & 1)];
    AdT[t] = f2bf(Ad[((size_t)e * 5504 + h) * 16 + (j & 15)]);
    return;
  }
  t -= 704512;
  if (t < 704512) {  // BgT: N=5504
    int j = t & 31;
    int n = (t >> 5) % 5504;
    int b = t / (5504 * 32);
    int e = (j & 16) ? sidx[2 * b + 1] : sidx[2 * b];
    BgT[t] = f2bf(Bg[((size_t)e * 16 + (j & 15)) * 5504 + n]);
    return;
  }
  t -= 704512;
  if (t < 704512) {  // BuT: N=5504
    int j = t & 31;
    int n = (t >> 5) % 5504;
    int b = t / (5504 * 32);
    int e = (j & 16) ? sidx[2 * b + 1] : sidx[2 * b];
    BuT[t] = f2bf(Bu[((size_t)e * 16 + (j & 15)) * 5504 + n]);
    return;
  }
  t -= 704512;
  if (t < 262144) {  // BdT: N=2048
    int j = t & 31;
    int n = (t >> 5) % 2048;
    int b = t / (2048 * 32);
    int e = (j & 16) ? sidx[2 * b + 1] : sidx[2 * b];
    BdT[t] = f2bf(Bd[((size_t)e * 16 + (j & 15)) * 2048 + n]);
  }
}

// ---- skinny MFMA GEMM with split-K (xa = xb @ AxT^T) ----
template <int N2>
__global__ __launch_bounds__(256) void k_skinny(
    const u16* __restrict__ A, const u16* __restrict__ BT,
    float* __restrict__ part, int M, int K, int total_iters, int iters_per_chunk) {
  __shared__ u16 sA[128 * 64];
  __shared__ u16 sB[N2 * 64];
  int nm = M >> 7;
  int bm = blockIdx.x % nm, chunk = blockIdx.x / nm;
  int m0 = bm << 7;
  int batch = m0 >> 11;
  int tid = threadIdx.x, lane = tid & 63, w = tid >> 6;
  int kb = chunk * iters_per_chunk;
  int ke = min(total_iters, kb + iters_per_chunk);

  const u16* Bb = BT + (size_t)batch * N2 * K;

  const u16* ga[4]; u16* la[4];
  #pragma unroll
  for (int t = 0; t < 4; ++t) {
    int cb = 4 * w + t;
    int q = cb * 64 + lane;
    int row = q >> 3;
    int c = (q & 7) ^ (row & 7);
    ga[t] = A + (size_t)(m0 + row) * K + (size_t)kb * 64 + c * 8;
    la[t] = sA + cb * 512;
  }
  constexpr int nB = N2 / 32;
  const u16* gb[nB]; u16* lb[nB];
  #pragma unroll
  for (int t = 0; t < nB; ++t) {
    int cb = nB * w + t;
    int q = cb * 64 + lane;
    int row = q >> 3;
    int c = (q & 7) ^ (row & 7);
    gb[t] = Bb + (size_t)row * K + (size_t)kb * 64 + c * 8;
    lb[t] = sB + cb * 512;
  }

  f32x4 acc[2][N2 / 16] = {};
  for (int kt = kb; kt < ke; ++kt) {
    #pragma unroll
    for (int t = 0; t < 4; ++t) { g2l16(ga[t], la[t]); ga[t] += 64; }
    #pragma unroll
    for (int t = 0; t < nB; ++t) { g2l16(gb[t], lb[t]); gb[t] += 64; }
    __syncthreads();
    #pragma unroll
    for (int ks = 0; ks < 2; ++ks) {
      int cb0 = ks * 4 + (lane >> 4);
      bf16x8 af[2], bfr[N2 / 16];
      #pragma unroll
      for (int mi = 0; mi < 2; ++mi) {
        int row = 32 * w + mi * 16 + (lane & 15);
        af[mi] = *(const bf16x8*)(sA + (row * 8 + (cb0 ^ (row & 7))) * 8);
      }
      #pragma unroll
      for (int ni = 0; ni < N2 / 16; ++ni) {
        int row = ni * 16 + (lane & 15);
        bfr[ni] = *(const bf16x8*)(sB + (row * 8 + (cb0 ^ (row & 7))) * 8);
      }
      #pragma unroll
      for (int mi = 0; mi < 2; ++mi)
        #pragma unroll
        for (int ni = 0; ni < N2 / 16; ++ni)
          acc[mi][ni] = __builtin_amdgcn_mfma_f32_16x16x32_bf16(
              af[mi], bfr[ni], acc[mi][ni], 0, 0, 0);
    }
    __syncthreads();
  }

  int rb = (lane >> 4) * 4, cc = lane & 15;
  #pragma unroll
  for (int mi = 0; mi < 2; ++mi)
    #pragma unroll
    for (int ni = 0; ni < N2 / 16; ++ni)
      #pragma unroll
      for (int reg = 0; reg < 4; ++reg) {
        int gr = m0 + 32 * w + mi * 16 + rb + reg;
        int gc = ni * 16 + cc;
        part[((size_t)chunk * M + gr) * N2 + gc] = acc[mi][ni][reg];
      }
}

// ---- finalize split-K: out = bf16(2 * sum_chunks part) ----
__global__ void k_fin(const float* __restrict__ part, u16* __restrict__ out0,
                      u16* __restrict__ out1, int M, int N2, int nch) {
  int t = blockIdx.x * 256 + threadIdx.x;
  if (t >= M * N2) return;
  float s = 0.f;
  for (int c = 0; c < nch; ++c) s += part[(size_t)c * M * N2 + t];
  int j = t % N2, bs = t / N2;
  u16 v = f2bf(2.0f * s);
  if (N2 == 64) {
    if (j < 32) out0[(size_t)bs * 32 + j] = v;
    else        out1[(size_t)bs * 32 + (j - 32)] = v;
  } else {
    out0[(size_t)bs * 32 + j] = v;
  }
}

// ---- ha finalize: bf16(2 * haf) ----
__global__ void k_haf(const float* __restrict__ haf, u16* __restrict__ ha) {
  int t = blockIdx.x * 256 + threadIdx.x;
  if (t < 262144) ha[t] = f2bf(2.0f * haf[t]);
}

// ================= fused gate+up GEMM (+ ha fold) =================
// One block computes both gate and up 128x128 tiles (A staged once), epilogue
// h = silu(g)*u -> gbuf, then the block's contribution to ha = h @ AdT^T is
// computed in-block (h tile -> dead sG/sU, AdT slice -> dead sA, 16 MFMA/wave)
// and atomicAdd'ed into fp32 haf. Removes the skinny<32> pass entirely.
__global__ __launch_bounds__(256, 2)
void k_gemmGU(const u16* __restrict__ A, const u16* __restrict__ Bg_,
              const u16* __restrict__ Bu_,
              const u16* __restrict__ A2g, const u16* __restrict__ A2u,
              const u16* __restrict__ B2g, const u16* __restrict__ B2u,
              const u16* __restrict__ AdT, float* __restrict__ haf,
              u16* __restrict__ Out, int N, int K) {
  __shared__ u16 sA[128 * 64];
  __shared__ u16 sG[128 * 64];
  __shared__ u16 sU[128 * 64];
  int nt = N >> 7;
  int nm = gridDim.x / nt;
  int perx = nm >> 3;
  int xcd = blockIdx.x & 7;
  int v = blockIdx.x >> 3;
  int bn = v / perx;
  int bm = xcd * perx + (v - bn * perx);
  int m0 = bm << 7, n0 = bn << 7;
  int batch = m0 >> 11;
  int tid = threadIdx.x, lane = tid & 63, w = tid >> 6;
  int mo = (w & 1) << 6, no = (w >> 1) << 6;

  const u16* ga[4]; const u16* gg[4]; const u16* gu[4];
  u16* la[4]; u16* lg[4]; u16* lu[4];
  #pragma unroll
  for (int t = 0; t < 4; ++t) {
    int cb = 4 * w + t;
    int q = cb * 64 + lane;
    int row = q >> 3;
    int c = (q & 7) ^ (row & 7);
    ga[t] = A + (size_t)(m0 + row) * K + c * 8;
    gg[t] = Bg_ + (size_t)(n0 + row) * K + c * 8;
    gu[t] = Bu_ + (size_t)(n0 + row) * K + c * 8;
    la[t] = sA + cb * 512;
    lg[t] = sG + cb * 512;
    lu[t] = sU + cb * 512;
  }

  f32x4 accg[4][4] = {};
  f32x4 accu[4][4] = {};

  int kiters = K >> 6;
  for (int kt = 0; kt < kiters; ++kt) {
    #pragma unroll
    for (int t = 0; t < 4; ++t) { g2l16(ga[t], la[t]); ga[t] += 64; }
    #pragma unroll
    for (int t = 0; t < 4; ++t) { g2l16(gg[t], lg[t]); gg[t] += 64; }
    #pragma unroll
    for (int t = 0; t < 4; ++t) { g2l16(gu[t], lu[t]); gu[t] += 64; }
    __syncthreads();
    #pragma unroll
    for (int ks = 0; ks < 2; ++ks) {
      bf16x8 af[4], bgf[4], buf_[4];
      int cb0 = ks * 4 + (lane >> 4);
      #pragma unroll
      for (int mi = 0; mi < 4; ++mi) {
        int row = mo + mi * 16 + (lane & 15);
        af[mi] = *(const bf16x8*)(sA + (row * 8 + (cb0 ^ (row & 7))) * 8);
      }
      #pragma unroll
      for (int ni = 0; ni < 4; ++ni) {
        int row = no + ni * 16 + (lane & 15);
        bgf[ni] = *(const bf16x8*)(sG + (row * 8 + (cb0 ^ (row & 7))) * 8);
        buf_[ni] = *(const bf16x8*)(sU + (row * 8 + (cb0 ^ (row & 7))) * 8);
      }
      #pragma unroll
      for (int mi = 0; mi < 4; ++mi)
        #pragma unroll
        for (int ni = 0; ni < 4; ++ni) {
          accg[mi][ni] = __builtin_amdgcn_mfma_f32_16x16x32_bf16(
              af[mi], bgf[ni], accg[mi][ni], 0, 0, 0);
          accu[mi][ni] = __builtin_amdgcn_mfma_f32_16x16x32_bf16(
              af[mi], buf_[ni], accu[mi][ni], 0, 0, 0);
        }
    }
    __syncthreads();
  }

  // LoRA extra K=32 step: gate uses (A2g,B2g), up uses (A2u,B2u)
  {
    const u16* B2gb = B2g + (size_t)batch * N * 32;
    const u16* B2ub = B2u + (size_t)batch * N * 32;
    #pragma unroll
    for (int t = 0; t < 2; ++t) {
      int cb = 2 * w + t;
      int q = cb * 64 + lane;
      int row = q >> 2;
      int c = (q & 3) ^ (row & 3);
      g2l16(A2g + (size_t)(m0 + row) * 32 + c * 8, sA + cb * 512);
      g2l16(A2u + (size_t)(m0 + row) * 32 + c * 8, sA + 4096 + cb * 512);
      g2l16(B2gb + (size_t)(n0 + row) * 32 + c * 8, sG + cb * 512);
      g2l16(B2ub + (size_t)(n0 + row) * 32 + c * 8, sU + cb * 512);
    }
    __syncthreads();
    int c0 = lane >> 4;
    bf16x8 ag2[4], au2[4], bg2[4], bu2[4];
    #pragma unroll
    for (int mi = 0; mi < 4; ++mi) {
      int row = mo + mi * 16 + (lane & 15);
      ag2[mi] = *(const bf16x8*)(sA + (row * 4 + (c0 ^ (row & 3))) * 8);
      au2[mi] = *(const bf16x8*)(sA + 4096 + (row * 4 + (c0 ^ (row & 3))) * 8);
    }
    #pragma unroll
    for (int ni = 0; ni < 4; ++ni) {
      int row = no + ni * 16 + (lane & 15);
      bg2[ni] = *(const bf16x8*)(sG + (row * 4 + (c0 ^ (row & 3))) * 8);
      bu2[ni] = *(const bf16x8*)(sU + (row * 4 + (c0 ^ (row & 3))) * 8);
    }
    #pragma unroll
    for (int mi = 0; mi < 4; ++mi)
      #pragma unroll
      for (int ni = 0; ni < 4; ++ni) {
        accg[mi][ni] = __builtin_amdgcn_mfma_f32_16x16x32_bf16(
            ag2[mi], bg2[ni], accg[mi][ni], 0, 0, 0);
        accu[mi][ni] = __builtin_amdgcn_mfma_f32_16x16x32_bf16(
            au2[mi], bu2[ni], accu[mi][ni], 0, 0, 0);
      }
  }

  __syncthreads();  // all LoRA LDS reads complete before overwriting sA/sG/sU

  // stage AdT[0..32)[n0 .. n0+128) into sA as two 64-col swizzled halves
  {
    const u16* AdTb = AdT + (size_t)batch * 32 * 5504;
    int q = w * 64 + lane;
    int row = q >> 3;
    int c = (q & 7) ^ (row & 7);
    #pragma unroll
    for (int half = 0; half < 2; ++half)
      g2l16(AdTb + (size_t)row * 5504 + n0 + half * 64 + c * 8,
            sA + half * 2048 + w * 512);
  }

  // epilogue: h = silu(g)*u -> global AND swizzled LDS (sG half0, sU half1)
  int rb = (lane >> 4) * 4;
  int cc = lane & 15;
  #pragma unroll
  for (int mi = 0; mi < 4; ++mi) {
    #pragma unroll
    for (int ni = 0; ni < 4; ++ni) {
      #pragma unroll
      for (int reg = 0; reg < 4; ++reg) {
        int gr = m0 + mo + mi * 16 + rb + reg;
        int gc = n0 + no + ni * 16 + cc;
        size_t pos = (size_t)gr * N + gc;
        float gvv = accg[mi][ni][reg];
        float uvv = accu[mi][ni][reg];
        gvv = gvv / (1.f + __expf(-gvv));
        u16 hv = f2bf(gvv * uvv);
        Out[pos] = hv;
        int cl = no + ni * 16 + cc;         // 0..127 block-local col
        u16* sH = (cl < 64) ? sG : sU;
        int c2 = cl & 63;
        int r2 = mo + mi * 16 + rb + reg;   // 0..127 block-local row
        sH[(r2 * 8 + ((c2 >> 3) ^ (r2 & 7))) * 8 + (c2 & 7)] = hv;
      }
    }
  }
  __syncthreads();  // drains AdT g2l16 + h ds_writes

  // mini-GEMM: wave w handles rows moh..moh+63 x n-half (w>>1)
  {
    int moh = (w & 1) << 6;
    int half = w >> 1;
    const u16* sH = half ? sU : sG;
    const u16* sAd = sA + half * 2048;
    f32x4 ah[4][2] = {};
    #pragma unroll
    for (int ks = 0; ks < 2; ++ks) {
      int cb0 = ks * 4 + (lane >> 4);
      bf16x8 afh[4], bfh[2];
      #pragma unroll
      for (int mi = 0; mi < 4; ++mi) {
        int row = moh + mi * 16 + (lane & 15);
        afh[mi] = *(const bf16x8*)(sH + (row * 8 + (cb0 ^ (row & 7))) * 8);
      }
      #pragma unroll
      for (int jf = 0; jf < 2; ++jf) {
        int row = jf * 16 + (lane & 15);
        bfh[jf] = *(const bf16x8*)(sAd + (row * 8 + (cb0 ^ (row & 7))) * 8);
      }
      #pragma unroll
      for (int mi = 0; mi < 4; ++mi)
        #pragma unroll
        for (int jf = 0; jf < 2; ++jf)
          ah[mi][jf] = __builtin_amdgcn_mfma_f32_16x16x32_bf16(
              afh[mi], bfh[jf], ah[mi][jf], 0, 0, 0);
    }
    #pragma unroll
    for (int mi = 0; mi < 4; ++mi)
      #pragma unroll
      for (int jf = 0; jf < 2; ++jf)
        #pragma unroll
        for (int reg = 0; reg < 4; ++reg)
          atomicAdd(haf + (size_t)(m0 + moh + mi * 16 + rb + reg) * 32 +
                        jf * 16 + cc,
                    ah[mi][jf][reg]);
  }
}

// ================= dual-m-tile down GEMM =================
// One block computes out tiles (m0, n0) and (m0+128, n0): Wd-tile staged ONCE,
// 32 MFMA per wave per K-step (same proven profile as k_gemmGU).
__global__ __launch_bounds__(256, 2)
void k_gemmD(const u16* __restrict__ A, const u16* __restrict__ Bm,
             const u16* __restrict__ A2, const u16* __restrict__ B2,
             float* __restrict__ Out, int N, int K) {
  __shared__ u16 sA0[128 * 64];
  __shared__ u16 sA1[128 * 64];
  __shared__ u16 sB[128 * 64];
  int nt = N >> 7;                  // 16
  int nm = gridDim.x / nt;          // 32 m-pairs
  int perx = nm >> 3;
  int xcd = blockIdx.x & 7;
  int v = blockIdx.x >> 3;
  int bn = v / perx;
  int bm = xcd * perx + (v - bn * perx);
  int m0 = bm << 8, n0 = bn << 7;
  int batch = m0 >> 11;             // 256-block never straddles a batch
  int tid = threadIdx.x, lane = tid & 63, w = tid >> 6;
  int mo = (w & 1) << 6, no = (w >> 1) << 6;

  const u16* ga0[4]; const u16* ga1[4]; const u16* gb[4];
  u16* la0[4]; u16* la1[4]; u16* lb[4];
  #pragma unroll
  for (int t = 0; t < 4; ++t) {
    int cb = 4 * w + t;
    int q = cb * 64 + lane;
    int row = q >> 3;
    int c = (q & 7) ^ (row & 7);
    ga0[t] = A + (size_t)(m0 + row) * K + c * 8;
    ga1[t] = A + (size_t)(m0 + 128 + row) * K + c * 8;
    gb[t]  = Bm + (size_t)(n0 + row) * K + c * 8;
    la0[t] = sA0 + cb * 512;
    la1[t] = sA1 + cb * 512;
    lb[t]  = sB + cb * 512;
  }

  f32x4 acc0[4][4] = {};
  f32x4 acc1[4][4] = {};

  int kiters = K >> 6;
  for (int kt = 0; kt < kiters; ++kt) {
    #pragma unroll
    for (int t = 0; t < 4; ++t) { g2l16(ga0[t], la0[t]); ga0[t] += 64; }
    #pragma unroll
    for (int t = 0; t < 4; ++t) { g2l16(ga1[t], la1[t]); ga1[t] += 64; }
    #pragma unroll
    for (int t = 0; t < 4; ++t) { g2l16(gb[t], lb[t]); gb[t] += 64; }
    __syncthreads();
    #pragma unroll
    for (int ks = 0; ks < 2; ++ks) {
      bf16x8 af0[4], af1[4], bfr[4];
      int cb0 = ks * 4 + (lane >> 4);
      #pragma unroll
      for (int mi = 0; mi < 4; ++mi) {
        int row = mo + mi * 16 + (lane & 15);
        af0[mi] = *(const bf16x8*)(sA0 + (row * 8 + (cb0 ^ (row & 7))) * 8);
        af1[mi] = *(const bf16x8*)(sA1 + (row * 8 + (cb0 ^ (row & 7))) * 8);
      }
      #pragma unroll
      for (int ni = 0; ni < 4; ++ni) {
        int row = no + ni * 16 + (lane & 15);
        bfr[ni] = *(const bf16x8*)(sB + (row * 8 + (cb0 ^ (row & 7))) * 8);
      }
      #pragma unroll
      for (int mi = 0; mi < 4; ++mi)
        #pragma unroll
        for (int ni = 0; ni < 4; ++ni) {
          acc0[mi][ni] = __builtin_amdgcn_mfma_f32_16x16x32_bf16(
              af0[mi], bfr[ni], acc0[mi][ni], 0, 0, 0);
          acc1[mi][ni] = __builtin_amdgcn_mfma_f32_16x16x32_bf16(
              af1[mi], bfr[ni], acc1[mi][ni], 0, 0, 0);
        }
    }
    __syncthreads();
  }

  // LoRA extra K=32 step: ha tiles at m0 and m0+128, BdT shared
  {
    const u16* B2b = B2 + (size_t)batch * N * 32;
    #pragma unroll
    for (int t = 0; t < 2; ++t) {
      int cb = 2 * w + t;
      int q = cb * 64 + lane;
      int row = q >> 2;
      int c = (q & 3) ^ (row & 3);
      g2l16(A2 + (size_t)(m0 + row) * 32 + c * 8, sA0 + cb * 512);
      g2l16(A2 + (size_t)(m0 + 128 + row) * 32 + c * 8, sA1 + cb * 512);
      g2l16(B2b + (size_t)(n0 + row) * 32 + c * 8, sB + cb * 512);
    }
    __syncthreads();
    int c0 = lane >> 4;
    bf16x8 af0[4], af1[4], bfr[4];
    #pragma unroll
    for (int mi = 0; mi < 4; ++mi) {
      int row = mo + mi * 16 + (lane & 15);
      af0[mi] = *(const bf16x8*)(sA0 + (row * 4 + (c0 ^ (row & 3))) * 8);
      af1[mi] = *(const bf16x8*)(sA1 + (row * 4 + (c0 ^ (row & 3))) * 8);
    }
    #pragma unroll
    for (int ni = 0; ni < 4; ++ni) {
      int row = no + ni * 16 + (lane & 15);
      bfr[ni] = *(const bf16x8*)(sB + (row * 4 + (c0 ^ (row & 3))) * 8);
    }
    #pragma unroll
    for (int mi = 0; mi < 4; ++mi)
      #pragma unroll
      for (int ni = 0; ni < 4; ++ni) {
        acc0[mi][ni] = __builtin_amdgcn_mfma_f32_16x16x32_bf16(
            af0[mi], bfr[ni], acc0[mi][ni], 0, 0, 0);
        acc1[mi][ni] = __builtin_amdgcn_mfma_f32_16x16x32_bf16(
            af1[mi], bfr[ni], acc1[mi][ni], 0, 0, 0);
      }
  }

  int rb = (lane >> 4) * 4;
  int cc = lane & 15;
  #pragma unroll
  for (int mi = 0; mi < 4; ++mi) {
    #pragma unroll
    for (int ni = 0; ni < 4; ++ni) {
      #pragma unroll
      for (int reg = 0; reg < 4; ++reg) {
        int gr = m0 + mo + mi * 16 + rb + reg;
        int gc = n0 + no + ni * 16 + cc;
        Out[(size_t)gr * N + gc] = acc0[mi][ni][reg];
        Out[(size_t)(gr + 128) * N + gc] = acc1[mi][ni][reg];
      }
    }
  }
}

extern "C" void kernel_launch(void* const* d_in, const int* in_sizes, int n_in,
                              void* d_out, int out_size, void* d_ws, size_t ws_size,
                              hipStream_t stream) {
  const float* x  = (const float*)d_in[0];
  const float* gv = (const float*)d_in[1];
  const float* Wg = (const float*)d_in[2];
  const float* Ag = (const float*)d_in[3];
  const float* Bg = (const float*)d_in[4];
  const float* Wu = (const float*)d_in[5];
  const float* Au = (const float*)d_in[6];
  const float* Bu = (const float*)d_in[7];
  const float* Wd = (const float*)d_in[8];
  const float* Ad = (const float*)d_in[9];
  const float* Bd = (const float*)d_in[10];
  float* out = (float*)d_out;

  char* ws = (char*)d_ws;
  size_t off = 0;
  auto alloc = [&](size_t bytes) -> void* {
    void* p = ws + off;
    off = (off + bytes + 255) & ~(size_t)255;
    return p;
  };
  u16* xb   = (u16*)alloc((size_t)8192 * 2048 * 2);
  u16* Wgb  = (u16*)alloc((size_t)5504 * 2048 * 2);
  u16* Wub  = (u16*)alloc((size_t)5504 * 2048 * 2);
  u16* Wdb  = (u16*)alloc((size_t)2048 * 5504 * 2);
  u16* xag  = (u16*)alloc((size_t)8192 * 32 * 2);
  u16* xau  = (u16*)alloc((size_t)8192 * 32 * 2);
  u16* ha   = (u16*)alloc((size_t)8192 * 32 * 2);
  u16* BgT  = (u16*)alloc((size_t)4 * 5504 * 32 * 2);
  u16* BuT  = (u16*)alloc((size_t)4 * 5504 * 32 * 2);
  u16* BdT  = (u16*)alloc((size_t)4 * 2048 * 32 * 2);
  u16* AxT  = (u16*)alloc((size_t)4 * 64 * 2048 * 2);
  u16* AdT  = (u16*)alloc((size_t)4 * 32 * 5504 * 2);
  float* haf = (float*)alloc((size_t)8192 * 32 * 4);
  u16* gbuf = (u16*)alloc((size_t)8192 * 5504 * 2);
  if (off > ws_size) return;

  // split-K partial buffer for xa lives in gbuf (dead until GU)
  float* part_xa = (float*)gbuf;   // 16*8192*64*4 = 33.5MB <= 90MB

  hipMemsetAsync(haf, 0, (size_t)8192 * 32 * 4, stream);

  // merged casts + LoRA prep: 49408 cast blocks + 11328 prep blocks
  k_pre<<<60736, 256, 0, stream>>>(x, xb, Wg, Wgb, Wu, Wub, Wd, Wdb,
                                   gv, Ag, Au, Ad, Bg, Bu, Bd,
                                   AxT, AdT, BgT, BuT, BdT);

  // xa: [8192 x 64] = xb @ AxT^T, split-K 16 chunks (K=2048)
  k_skinny<64><<<64 * 16, 256, 0, stream>>>(xb, AxT, part_xa, 8192, 2048, 32, 2);
  k_fin<<<2048, 256, 0, stream>>>(part_xa, xag, xau, 8192, 64, 16);

  // fused gate+up (+ ha fold): h -> gbuf, ha partials -> haf
  k_gemmGU<<<64 * 43, 256, 0, stream>>>(xb, Wgb, Wub, xag, xau, BgT, BuT,
                                        AdT, haf, gbuf, 5504, 2048);

  // ha = bf16(2 * haf)
  k_haf<<<1024, 256, 0, stream>>>(haf, ha);

  // down: out = h@Wd^T + lora (fp32), dual-m-tile blocks
  k_gemmD<<<32 * 16, 256, 0, stream>>>(gbuf, Wdb, ha, BdT, out, 2048, 5504);
}